// Round 17
// baseline (808.341 us; speedup 1.0000x reference)
//
#include <hip/hip_runtime.h>
#include <cstdint>

#define U64 unsigned long long

static constexpr int H = 38, W = 50, P = 1900;        // feature map
static constexpr int CIN = 2048, CMID = 256;
static constexpr int NA = 9, NBOX = 17100;            // 1900*9
static constexpr int HP = 40, WP = 52, QP = HP * WP;  // padded positions (2080)
static constexpr int TPITCH = 2084;                   // in_tT row pitch (floats), mult of 4
static constexpr int KS = 7;                          // split-K over cin
static constexpr int NW = 268;                        // u64 words covering NBOX bits
static constexpr int MSTRIDE = 272;                   // mask row stride (words)
static constexpr int NG = 67;                         // 256-box groups
static constexpr float NMS_T = 0.5f;
static constexpr int QTILE = 64;                      // 32 tiles cover q 0..2047
static constexpr int SROW = 180;                      // s_in row stride (floats)

// ---------------- ws layout (bytes) ----------------
static constexpr size_t SZ_INT  = (size_t)CIN * TPITCH * 4;   // 17,072,128
static constexpr size_t SZ_WT   = (size_t)9 * CIN * CMID * 4; // 18,874,368
static constexpr size_t SZ_PART = (size_t)KS * P * CMID * 4;  // 13,619,200
static constexpr size_t OFF_INT  = 0;
static constexpr size_t OFF_WT   = OFF_INT + SZ_INT;
static constexpr size_t OFF_PART = OFF_WT + SZ_WT;
static constexpr size_t REGA     = OFF_PART + SZ_PART;        // 49,565,696
// region A overlay (dead after k_reduce): mask + diag 256-blocks
static constexpr size_t OFF_MASK = 0;                          // mask [NBOX][MSTRIDE] (37.2 MB)
static constexpr size_t SZ_MASK  = (size_t)NBOX * MSTRIDE * 8; // 37,209,600
static constexpr size_t OFF_DIAG = SZ_MASK;                    // diagX [67][4][4][64] u64 (549 KB)
static constexpr size_t SZ_DIAG  = (size_t)NG * 1024 * 8;      // 548,864
static constexpr size_t OFF_MID  = REGA;
static constexpr size_t OFF_FG   = OFF_MID + 1945600;
static constexpr size_t OFF_BOX  = OFF_FG + 68608;
static constexpr size_t OFF_SBOX = OFF_BOX + 273664;
static constexpr size_t OFF_SAREA= OFF_SBOX + 273664;
static constexpr size_t OFF_CNT  = OFF_SAREA + 68608;
static constexpr size_t WS_NEED  = OFF_CNT + 68608;            // ~52.26 MB (unchanged)

__device__ __forceinline__ U64 rdlane64(U64 v, int l) {
    unsigned lo = (unsigned)__builtin_amdgcn_readlane((int)(unsigned)(v & 0xffffffffull), l);
    unsigned hi = (unsigned)__builtin_amdgcn_readlane((int)(unsigned)(v >> 32), l);
    return ((U64)hi << 32) | (U64)lo;
}

__device__ __forceinline__ U64 vmaskw(int wg) {
    int rem = NBOX - wg * 64;
    if (rem >= 64) return ~0ull;
    if (rem <= 0) return 0ull;
    return (1ull << rem) - 1ull;
}

// ---------------- kernels ----------------

__global__ __launch_bounds__(256) void k_sentinel(float* out, int n) {
    int i = blockIdx.x * 256 + threadIdx.x;
    if (i < n) out[i] = 1.2345678e8f;
}

// feature_map [CIN][H][W] -> in_tT [CIN][TPITCH] (padded image rows; memset first)
__global__ __launch_bounds__(256) void k_in_t(const float* __restrict__ fm, float* __restrict__ in_tT) {
    int idx = blockIdx.x * 256 + threadIdx.x;
    if (idx >= CIN * (H * W)) return;
    int ci = idx / (H * W), hw = idx - ci * (H * W);
    int h = hw / W, w = hw - h * W;
    in_tT[(size_t)ci * TPITCH + (h + 1) * WP + 1 + w] = fm[idx];
}

// conv_w [CMID][CIN][3][3] -> w2 [y(8)][sub(4)][ci(2048)][k(9)][c(8)]
__global__ __launch_bounds__(256) void k_w_t(const float* __restrict__ cw, float* __restrict__ w2) {
    int idx = blockIdx.x * 256 + threadIdx.x;
    if (idx >= CMID * CIN * 9) return;
    int co = idx / (CIN * 9);
    int rem = idx - co * (CIN * 9);
    int ci = rem / 9, k = rem - ci * 9;
    w2[((size_t)(co >> 3) * CIN + ci) * 72 + k * 8 + (co & 7)] = cw[idx];
}

// 3x3 conv, split-K. grid 1792 = 32 qtiles of 64 x 8 cout-groups x 7 z
// (XCD-swizzled, z-major; 7 blocks/CU for TLP). Lane L owns q = q0+L;
// scalar stride-1 LDS reads (proven conflict-free).
__global__ __launch_bounds__(256, 2) void k_conv(const float* __restrict__ in_tT,
                                                 const float* __restrict__ w2,
                                                 float* __restrict__ partial) {
    __shared__ float s_in[16 * SROW];    // 16 ci x 180 floats (11.5 KB)
    int t = threadIdx.x;
    int lane = t & 63;
    int sub = __builtin_amdgcn_readfirstlane(t >> 6);   // wave-uniform SGPR

    int raw = blockIdx.x;
    int xcd = raw & 7, i0 = raw >> 3;
    int L = xcd * 224 + i0;          // 1792 = 8*224, bijective
    int z = L >> 8;                  // 7 z-slices (256 blocks each)
    int r0 = L & 255;
    int by = r0 >> 5, bx = r0 & 31;
    int q0 = bx * QTILE;
    int cout0 = by * 32;
    int cin0 = (z <= 1) ? 304 * z : 608 + 288 * (z - 2);   // 304,304,288x5
    int cin1 = cin0 + ((z <= 1) ? 304 : 288);

    float acc[8];
#pragma unroll
    for (int c = 0; c < 8; ++c) acc[c] = 0.f;

    const float* wbase = w2 + (size_t)(by * 4 + sub) * CIN * 72;

    for (int c0 = cin0; c0 < cin1; c0 += 16) {
        // stage 16 ci rows: 44 quads each covering q in [q0-56, q0+120)
        for (int idx = t; idx < 16 * 44; idx += 256) {
            int r = idx / 44, j = idx - r * 44;
            int qf = q0 - 56 + 4 * j;
            float4 v = make_float4(0.f, 0.f, 0.f, 0.f);
            if (qf >= 0 && qf <= 2080)
                v = *reinterpret_cast<const float4*>(in_tT + (size_t)(c0 + r) * TPITCH + qf);
            *reinterpret_cast<float4*>(s_in + r * SROW + 4 * j) = v;
        }
        __syncthreads();
#pragma unroll 1
        for (int r = 0; r < 16; ++r) {
            const float* si = s_in + r * SROW + lane + 56;
            const float4* w4 = reinterpret_cast<const float4*>(wbase + (size_t)(c0 + r) * 72);
#pragma unroll
            for (int k = 0; k < 9; ++k) {
                const int DQ[9] = {-53, -52, -51, -1, 0, 1, 51, 52, 53};
                float iv0 = si[DQ[k]];
                float4 wa = w4[k * 2], wb = w4[k * 2 + 1];
                acc[0] += iv0 * wa.x; acc[1] += iv0 * wa.y;
                acc[2] += iv0 * wa.z; acc[3] += iv0 * wa.w;
                acc[4] += iv0 * wb.x; acc[5] += iv0 * wb.y;
                acc[6] += iv0 * wb.z; acc[7] += iv0 * wb.w;
            }
        }
        __syncthreads();
    }
    float* part = partial + (size_t)z * P * CMID;
    {
        int q = q0 + lane;
        if (q < QP) {
            int hp = q / WP, wp_ = q - hp * WP;
            if (hp >= 1 && hp <= H && wp_ >= 1 && wp_ <= W) {
                int p = (hp - 1) * W + (wp_ - 1);
                float* dst = part + (size_t)p * CMID + cout0 + sub * 8;
                float4* d4 = reinterpret_cast<float4*>(dst);
                d4[0] = make_float4(acc[0], acc[1], acc[2], acc[3]);
                d4[1] = make_float4(acc[4], acc[5], acc[6], acc[7]);
            }
        }
    }
}

// sum partials + bias + relu -> mid [P][CMID]
__global__ __launch_bounds__(256) void k_reduce(const float* __restrict__ partial,
                                                const float* __restrict__ bias,
                                                float* __restrict__ mid) {
    int p = blockIdx.x, c = threadIdx.x;
    float s = bias[c];
    for (int ks = 0; ks < KS; ++ks) s += partial[(size_t)ks * P * CMID + (size_t)p * CMID + c];
    mid[(size_t)p * CMID + c] = fmaxf(s, 0.f);
}

// 1x1 heads + softmax + anchors + loc2bbox + clip. 16 positions per block (4 reps).
__global__ __launch_bounds__(256) void k_heads(const float* __restrict__ mid,
                                               const float* __restrict__ score_w,
                                               const float* __restrict__ score_b,
                                               const float* __restrict__ loc_w,
                                               const float* __restrict__ loc_b,
                                               float* __restrict__ score_out,
                                               float* __restrict__ loc_out,
                                               float* __restrict__ anch_out,
                                               float* __restrict__ fg,
                                               float* __restrict__ boxes) {
    __shared__ float wl[256][56];
    __shared__ float bias[56];
    __shared__ float dots[4][64];
    int t = threadIdx.x;
    for (int idx = t; idx < 18 * 256; idx += 256) {
        int c = idx >> 8, i = idx & 255;
        wl[i][c] = score_w[idx];
    }
    for (int idx = t; idx < 36 * 256; idx += 256) {
        int c = idx >> 8, i = idx & 255;
        wl[i][18 + c] = loc_w[idx];
    }
    if (t < 18) bias[t] = score_b[t];
    else if (t < 54) bias[t] = loc_b[t - 18];
    __syncthreads();

    int pl = t >> 6, c = t & 63;
    for (int rep = 0; rep < 4; ++rep) {
        int p = blockIdx.x * 16 + rep * 4 + pl;
        if (c < 54 && p < P) {
            float d = bias[c];
            const float4* mp = reinterpret_cast<const float4*>(mid + (size_t)p * CMID);
            for (int i4 = 0; i4 < 64; ++i4) {
                float4 m4 = mp[i4];
                int i = i4 * 4;
                d += m4.x * wl[i][c] + m4.y * wl[i + 1][c] + m4.z * wl[i + 2][c] + m4.w * wl[i + 3][c];
            }
            dots[pl][c] = d;
        }
        __syncthreads();
        if (c < NA && p < P) {
            int a = c;
            int idx = p * NA + a;
            float l0 = dots[pl][2 * a], l1 = dots[pl][2 * a + 1];
            float mx = fmaxf(l0, l1);
            float e0 = expf(l0 - mx), e1 = expf(l1 - mx);
            float den = e0 + e1;
            float s0 = e0 / den, s1 = e1 / den;
            score_out[(size_t)idx * 2 + 0] = s0;
            score_out[(size_t)idx * 2 + 1] = s1;
            fg[idx] = s1;
            float dx = dots[pl][18 + 4 * a + 0];
            float dy = dots[pl][18 + 4 * a + 1];
            float dw = dots[pl][18 + 4 * a + 2];
            float dh = dots[pl][18 + 4 * a + 3];
            loc_out[(size_t)idx * 4 + 0] = dx;
            loc_out[(size_t)idx * 4 + 1] = dy;
            loc_out[(size_t)idx * 4 + 2] = dw;
            loc_out[(size_t)idx * 4 + 3] = dh;
            int hh = p / W, ww = p % W;
            const double scales[3] = {8.0, 16.0, 32.0};
            const double ratios[3] = {0.5, 1.0, 2.0};
            double s = scales[a / 3], r = ratios[a % 3];
            double wb2 = 16.0 * s * sqrt(r);
            double hb = wb2 / r;
            double xmin = 8.0 - wb2 / 2.0, ymin = 8.0 - hb / 2.0;
            float b0 = (float)xmin, b1 = (float)ymin;
            float b2 = (float)(xmin + wb2), b3 = (float)(ymin + hb);
            float gx = (float)(ww * 16), gy = (float)(hh * 16);
            float a0 = gx + b0, a1 = gy + b1, a2 = gx + b2, a3 = gy + b3;
            anch_out[(size_t)idx * 4 + 0] = a0;
            anch_out[(size_t)idx * 4 + 1] = a1;
            anch_out[(size_t)idx * 4 + 2] = a2;
            anch_out[(size_t)idx * 4 + 3] = a3;
            float aw = a2 - a0, ah = a3 - a1;
            float cx = a0 + 0.5f * aw, cy = a1 + 0.5f * ah;
            float ncx = dx * aw + cx, ncy = dy * ah + cy;
            float nw = expf(dw) * aw, nh = expf(dh) * ah;
            float x1 = ncx - 0.5f * nw, y1 = ncy - 0.5f * nh;
            float x2 = ncx + 0.5f * nw, y2 = ncy + 0.5f * nh;
            x1 = fminf(fmaxf(x1, 0.f), (float)(W * 16));
            x2 = fminf(fmaxf(x2, 0.f), (float)(W * 16));
            y1 = fminf(fmaxf(y1, 0.f), (float)(H * 16));
            y2 = fminf(fmaxf(y2, 0.f), (float)(H * 16));
            float4* bp = reinterpret_cast<float4*>(boxes);
            bp[idx] = make_float4(x1, y1, x2, y2);
        }
        __syncthreads();
    }
}

// partial stable-descending rank counts over a j-slice. grid (67, 8)
static constexpr int JSL = 2144;  // slice size (mult of 4)
__global__ __launch_bounds__(256) void k_rank_part(const float* __restrict__ fg,
                                                   int* __restrict__ cntb) {
    __shared__ float4 tile[256];
    int t = threadIdx.x;
    int i = blockIdx.x * 256 + t;
    int j0 = blockIdx.y * JSL;
    int j1 = min(NBOX, j0 + JSL);
    float my = (i < NBOX) ? fg[i] : 0.f;
    int cnt = 0;
    for (int base = j0; base < j1; base += 1024) {
        int j = base + t * 4;
        float4 v = make_float4(-3.4e38f, -3.4e38f, -3.4e38f, -3.4e38f);
        if (j + 3 < j1) {
            v = *reinterpret_cast<const float4*>(fg + j);
        } else {
            if (j < j1) v.x = fg[j];
            if (j + 1 < j1) v.y = fg[j + 1];
            if (j + 2 < j1) v.z = fg[j + 2];
            if (j + 3 < j1) v.w = fg[j + 3];
        }
        __syncthreads();
        tile[t] = v;
        __syncthreads();
        if (i < NBOX) {
            for (int u = 0; u < 256; ++u) {
                float4 s = tile[u];
                int jb = base + u * 4;
                cnt += (s.x > my) || (s.x == my && jb < i);
                cnt += (s.y > my) || (s.y == my && jb + 1 < i);
                cnt += (s.z > my) || (s.z == my && jb + 2 < i);
                cnt += (s.w > my) || (s.w == my && jb + 3 < i);
            }
        }
    }
    if (i < NBOX && cnt) atomicAdd(&cntb[i], cnt);
}

// scatter boxes to sorted order using rank counts
__global__ __launch_bounds__(256) void k_scatter(const int* __restrict__ cntb,
                                                 const float* __restrict__ boxes,
                                                 float* __restrict__ sboxes,
                                                 float* __restrict__ sarea) {
    int i = blockIdx.x * 256 + threadIdx.x;
    if (i >= NBOX) return;
    int c = cntb[i];
    float4 b = reinterpret_cast<const float4*>(boxes)[i];
    reinterpret_cast<float4*>(sboxes)[c] = b;
    sarea[c] = (b.z - b.x) * (b.w - b.y);
}

// NMS pair bitmask, row-major + diag 256-block bands (diagX memset 0 first).
__global__ __launch_bounds__(256) void k_maskfill(const float* __restrict__ sboxes,
                                                  const float* __restrict__ sarea,
                                                  U64* __restrict__ mask,
                                                  U64* __restrict__ diagX) {
    int w = blockIdx.y;
    int i0 = blockIdx.x * 256;
    if (w < (i0 >> 6)) return;
    __shared__ float4 sb[64];
    __shared__ float sa[64];
    int t = threadIdx.x;
    if (t < 64) {
        int j = w * 64 + t;
        if (j < NBOX) {
            sb[t] = reinterpret_cast<const float4*>(sboxes)[j];
            sa[t] = sarea[j];
        } else {
            sb[t] = make_float4(0.f, 0.f, 0.f, 0.f);
            sa[t] = 0.f;
        }
    }
    __syncthreads();
    int i = i0 + t;
    if (i >= NBOX || w < (i >> 6)) return;
    float4 bi = reinterpret_cast<const float4*>(sboxes)[i];
    float ai = sarea[i];
    U64 word = 0;
#pragma unroll 4
    for (int jb = 0; jb < 64; ++jb) {
        int j = w * 64 + jb;
        float4 bj = sb[jb];
        float xx1 = fmaxf(bi.x, bj.x), yy1 = fmaxf(bi.y, bj.y);
        float xx2 = fminf(bi.z, bj.z), yy2 = fminf(bi.w, bj.w);
        float inter = fmaxf(xx2 - xx1, 0.f) * fmaxf(yy2 - yy1, 0.f);
        float iou = inter / (ai + sa[jb] - inter);
        word |= ((U64)((iou > NMS_T) && (j > i))) << jb;
    }
    mask[(size_t)i * MSTRIDE + w] = word;
    int gi = i >> 8;
    int wl = w - gi * 4;
    if (wl >= 0 && wl < 4)
        diagX[(size_t)gi * 1024 + wl * 256 + (i & 255)] = word;
}

// ---- sweep v9: single wave, asm-pinned pipeline (round-12, unchanged).
#define GLOAD64(dst, addr) \
    asm volatile("global_load_dwordx2 %0, %1, off" : "=v"(dst) : "v"(addr))

#define VWAIT0() do { asm volatile("s_waitcnt vmcnt(0)" ::: "memory"); \
                      __builtin_amdgcn_sched_barrier(0); } while (0)

#define DVARS(P) U64 P##00, P##01, P##02, P##03, P##10, P##11, P##12, P##13, \
                     P##20, P##21, P##22, P##23, P##30, P##31, P##32, P##33

#define DISSUE(P, G) do { \
    const U64* _dp = diagX + (size_t)(G) * 1024 + lane; \
    GLOAD64(P##00, _dp +   0); GLOAD64(P##01, _dp +  64); GLOAD64(P##02, _dp + 128); GLOAD64(P##03, _dp + 192); \
    GLOAD64(P##10, _dp + 256); GLOAD64(P##11, _dp + 320); GLOAD64(P##12, _dp + 384); GLOAD64(P##13, _dp + 448); \
    GLOAD64(P##20, _dp + 512); GLOAD64(P##21, _dp + 576); GLOAD64(P##22, _dp + 640); GLOAD64(P##23, _dp + 704); \
    GLOAD64(P##30, _dp + 768); GLOAD64(P##31, _dp + 832); GLOAD64(P##32, _dp + 896); GLOAD64(P##33, _dp + 960); \
} while (0)

#define ZEROD(P) do { \
    P##00 = P##01 = P##02 = P##03 = P##10 = P##11 = P##12 = P##13 = 0; \
    P##20 = P##21 = P##22 = P##23 = P##30 = P##31 = P##32 = P##33 = 0; \
} while (0)

#define POPR(R) \
    int R; \
    do { \
        if (kk0) { int _i = (int)__builtin_ctzll(kk0); kk0 &= kk0 - 1; R = _i; } \
        else if (kk1) { int _i = (int)__builtin_ctzll(kk1); kk1 &= kk1 - 1; R = 64 + _i; } \
        else if (kk2) { int _i = (int)__builtin_ctzll(kk2); kk2 &= kk2 - 1; R = 128 + _i; } \
        else if (kk3) { int _i = (int)__builtin_ctzll(kk3); kk3 &= kk3 - 1; R = 192 + _i; } \
        else R = -1; \
    } while (0)

__global__ __launch_bounds__(64, 1) void k_sweep(const U64* __restrict__ mask,
                                                 const U64* __restrict__ diagX,
                                                 const float* __restrict__ sboxes,
                                                 float* __restrict__ rois_out,
                                                 float* __restrict__ keep_out) {
    int lane = threadIdx.x;
    U64 m0 = 0, m1 = 0, m2 = 0, m3 = 0, m4 = 0;
    unsigned base = 0;
    DVARS(c);
    DVARS(n);
    DISSUE(c, 0);
    VWAIT0();

    for (int g = 0; g < NG; ++g) {
        if (g + 1 < NG) { DISSUE(n, g + 1); } else { ZEROD(n); }

        const int gbase = g * 256;
        int rsel = g >> 4;
        U64 msel = (rsel == 0) ? m0 : (rsel == 1) ? m1 : (rsel == 2) ? m2 : (rsel == 3) ? m3 : m4;
        int lb = (g * 4) & 63;
        U64 mc0 = rdlane64(msel, lb), mc1 = rdlane64(msel, lb + 1);
        U64 mc2 = rdlane64(msel, lb + 2), mc3 = rdlane64(msel, lb + 3);
        U64 ns0 = ~mc0 & vmaskw(g * 4),     ns1 = ~mc1 & vmaskw(g * 4 + 1);
        U64 ns2 = ~mc2 & vmaskw(g * 4 + 2), ns3 = ~mc3 & vmaskw(g * 4 + 3);
        U64 k0 = 0, k1 = 0, k2 = 0, k3 = 0;
        while (ns0) {
            int i = (int)__builtin_ctzll(ns0);
            k0 |= 1ull << i;
            ns0 &= ~(rdlane64(c00, i) | (1ull << i));
            ns1 &= ~rdlane64(c10, i);
            ns2 &= ~rdlane64(c20, i);
            ns3 &= ~rdlane64(c30, i);
        }
        while (ns1) {
            int i = (int)__builtin_ctzll(ns1);
            k1 |= 1ull << i;
            ns1 &= ~(rdlane64(c11, i) | (1ull << i));
            ns2 &= ~rdlane64(c21, i);
            ns3 &= ~rdlane64(c31, i);
        }
        while (ns2) {
            int i = (int)__builtin_ctzll(ns2);
            k2 |= 1ull << i;
            ns2 &= ~(rdlane64(c22, i) | (1ull << i));
            ns3 &= ~rdlane64(c32, i);
        }
        while (ns3) {
            int i = (int)__builtin_ctzll(ns3);
            k3 |= 1ull << i;
            ns3 &= ~(rdlane64(c33, i) | (1ull << i));
        }
        unsigned p0 = (unsigned)__popcll(k0), p1 = (unsigned)__popcll(k1);
        unsigned p2 = (unsigned)__popcll(k2), p3 = (unsigned)__popcll(k3);
        U64 lmask = (1ull << lane) - 1ull;
        if ((k0 >> lane) & 1) {
            unsigned dst = base + (unsigned)__popcll(k0 & lmask);
            reinterpret_cast<float4*>(rois_out)[dst] = reinterpret_cast<const float4*>(sboxes)[gbase + lane];
            keep_out[dst] = 1.0f;
        }
        if ((k1 >> lane) & 1) {
            unsigned dst = base + p0 + (unsigned)__popcll(k1 & lmask);
            reinterpret_cast<float4*>(rois_out)[dst] = reinterpret_cast<const float4*>(sboxes)[gbase + 64 + lane];
            keep_out[dst] = 1.0f;
        }
        if ((k2 >> lane) & 1) {
            unsigned dst = base + p0 + p1 + (unsigned)__popcll(k2 & lmask);
            reinterpret_cast<float4*>(rois_out)[dst] = reinterpret_cast<const float4*>(sboxes)[gbase + 128 + lane];
            keep_out[dst] = 1.0f;
        }
        if ((k3 >> lane) & 1) {
            unsigned dst = base + p0 + p1 + p2 + (unsigned)__popcll(k3 & lmask);
            reinterpret_cast<float4*>(rois_out)[dst] = reinterpret_cast<const float4*>(sboxes)[gbase + 192 + lane];
            keep_out[dst] = 1.0f;
        }
        base += p0 + p1 + p2 + p3;

        const int wmin = g * 4 + 4;
        const bool gw0 = (lane >= wmin);
        const bool gw1 = (64 + lane >= wmin);
        const bool gw2 = (128 + lane >= wmin);
        const bool gw3 = (192 + lane >= wmin);
        const bool gw4 = (256 + lane >= wmin) && (256 + lane < NW);
        U64 kk0 = k0, kk1 = k1, kk2 = k2, kk3 = k3;
        bool any = (kk0 | kk1 | kk2 | kk3) != 0;
        while (kk0 | kk1 | kk2 | kk3) {
            POPR(ra); POPR(rb); POPR(rc); POPR(rd);
            if (rb < 0) rb = ra;
            if (rc < 0) rc = ra;
            if (rd < 0) rd = ra;
            const U64* qa = mask + (size_t)(gbase + ra) * MSTRIDE + lane;
            const U64* qb = mask + (size_t)(gbase + rb) * MSTRIDE + lane;
            const U64* qc = mask + (size_t)(gbase + rc) * MSTRIDE + lane;
            const U64* qd = mask + (size_t)(gbase + rd) * MSTRIDE + lane;
            U64 va0, va1, va2, va3, va4, vb0, vb1, vb2, vb3, vb4;
            U64 vc0, vc1, vc2, vc3, vc4, vd0, vd1, vd2, vd3, vd4;
            GLOAD64(va0, qa);       GLOAD64(va1, qa + 64);  GLOAD64(va2, qa + 128);
            GLOAD64(va3, qa + 192); GLOAD64(va4, qa + 256);
            GLOAD64(vb0, qb);       GLOAD64(vb1, qb + 64);  GLOAD64(vb2, qb + 128);
            GLOAD64(vb3, qb + 192); GLOAD64(vb4, qb + 256);
            GLOAD64(vc0, qc);       GLOAD64(vc1, qc + 64);  GLOAD64(vc2, qc + 128);
            GLOAD64(vc3, qc + 192); GLOAD64(vc4, qc + 256);
            GLOAD64(vd0, qd);       GLOAD64(vd1, qd + 64);  GLOAD64(vd2, qd + 128);
            GLOAD64(vd3, qd + 192); GLOAD64(vd4, qd + 256);
            VWAIT0();
            if (gw0) m0 |= va0 | vb0 | vc0 | vd0;
            if (gw1) m1 |= va1 | vb1 | vc1 | vd1;
            if (gw2) m2 |= va2 | vb2 | vc2 | vd2;
            if (gw3) m3 |= va3 | vb3 | vc3 | vd3;
            if (gw4) m4 |= va4 | vb4 | vc4 | vd4;
        }
        if (!any) VWAIT0();

        c00 = n00; c01 = n01; c02 = n02; c03 = n03;
        c10 = n10; c11 = n11; c12 = n12; c13 = n13;
        c20 = n20; c21 = n21; c22 = n22; c23 = n23;
        c30 = n30; c31 = n31; c32 = n32; c33 = n33;
    }
}

// ---------------- launch ----------------
extern "C" void kernel_launch(void* const* d_in, const int* in_sizes, int n_in,
                              void* d_out, int out_size, void* d_ws, size_t ws_size,
                              hipStream_t stream) {
    const float* fm      = (const float*)d_in[0];
    const float* conv_w  = (const float*)d_in[2];
    const float* conv_b  = (const float*)d_in[3];
    const float* score_w = (const float*)d_in[4];
    const float* score_b = (const float*)d_in[5];
    const float* loc_w   = (const float*)d_in[6];
    const float* loc_b   = (const float*)d_in[7];

    float* out = (float*)d_out;
    float* rois_out  = out;
    float* keep_out  = out + NBOX * 4;
    float* anch_out  = out + NBOX * 5;
    float* loc_out   = out + NBOX * 9;
    float* score_out = out + NBOX * 13;

    if (ws_size < WS_NEED) {
        k_sentinel<<<(out_size + 255) / 256, 256, 0, stream>>>(out, out_size);
        return;
    }

    char* ws = (char*)d_ws;
    float* in_tT   = (float*)(ws + OFF_INT);
    float* w2      = (float*)(ws + OFF_WT);
    float* partial = (float*)(ws + OFF_PART);
    U64*   mask    = (U64*)(ws + OFF_MASK);
    U64*   diagX   = (U64*)(ws + OFF_DIAG);
    float* mid     = (float*)(ws + OFF_MID);
    float* fg      = (float*)(ws + OFF_FG);
    float* boxes   = (float*)(ws + OFF_BOX);
    float* sboxes  = (float*)(ws + OFF_SBOX);
    float* sarea   = (float*)(ws + OFF_SAREA);
    int*   cntb    = (int*)(ws + OFF_CNT);

    hipMemsetAsync(in_tT, 0, SZ_INT, stream);
    k_in_t<<<(CIN * H * W + 255) / 256, 256, 0, stream>>>(fm, in_tT);
    k_w_t<<<(CMID * CIN * 9 + 255) / 256, 256, 0, stream>>>(conv_w, w2);
    k_conv<<<1792, 256, 0, stream>>>(in_tT, w2, partial);
    k_reduce<<<P, 256, 0, stream>>>(partial, conv_b, mid);
    k_heads<<<(P + 15) / 16, 256, 0, stream>>>(mid, score_w, score_b, loc_w, loc_b,
                                               score_out, loc_out, anch_out, fg, boxes);
    hipMemsetAsync(cntb, 0, NBOX * 4, stream);
    k_rank_part<<<dim3((NBOX + 255) / 256, 8), 256, 0, stream>>>(fg, cntb);
    k_scatter<<<(NBOX + 255) / 256, 256, 0, stream>>>(cntb, boxes, sboxes, sarea);
    hipMemsetAsync(rois_out, 0, (size_t)NBOX * 5 * 4, stream);  // rois_out + keep
    hipMemsetAsync(diagX, 0, SZ_DIAG, stream);
    k_maskfill<<<dim3((NBOX + 255) / 256, NW), 256, 0, stream>>>(sboxes, sarea, mask, diagX);
    k_sweep<<<1, 64, 0, stream>>>(mask, diagX, sboxes, rois_out, keep_out);
}

// Round 19
// 752.005 us; speedup vs baseline: 1.0749x; 1.0749x over previous
//
#include <hip/hip_runtime.h>
#include <cstdint>

#define U64 unsigned long long

static constexpr int H = 38, W = 50, P = 1900;        // feature map
static constexpr int CIN = 2048, CMID = 256;
static constexpr int NA = 9, NBOX = 17100;            // 1900*9
static constexpr int HP = 40, WP = 52, QP = HP * WP;  // padded positions (2080)
static constexpr int TPITCH = 2084;                   // in_tT row pitch (floats), mult of 4
static constexpr int KS = 7;                          // split-K over cin
static constexpr int NW = 268;                        // u64 words covering NBOX bits
static constexpr int MSTRIDE = 272;                   // mask row stride (words)
static constexpr int NG = 67;                         // 256-box groups
static constexpr float NMS_T = 0.5f;
static constexpr int QTILE = 128;                     // proven optimum (299/277/336 for 256/128/64)
static constexpr int SROW = 244;                      // s_in row stride (floats)

// ---------------- ws layout (bytes) ----------------
static constexpr size_t SZ_INT  = (size_t)CIN * TPITCH * 4;   // 17,072,128
static constexpr size_t SZ_WT   = (size_t)9 * CIN * CMID * 4; // 18,874,368
static constexpr size_t SZ_PART = (size_t)KS * P * CMID * 4;  // 13,619,200
static constexpr size_t OFF_INT  = 0;
static constexpr size_t OFF_WT   = OFF_INT + SZ_INT;
static constexpr size_t OFF_PART = OFF_WT + SZ_WT;
static constexpr size_t REGA     = OFF_PART + SZ_PART;        // 49,565,696
// region A overlay (dead after k_reduce): mask + diag 256-blocks
static constexpr size_t OFF_MASK = 0;                          // mask [NBOX][MSTRIDE] (37.2 MB)
static constexpr size_t SZ_MASK  = (size_t)NBOX * MSTRIDE * 8; // 37,209,600
static constexpr size_t OFF_DIAG = SZ_MASK;                    // diagX [67][4][4][64] u64 (549 KB)
static constexpr size_t SZ_DIAG  = (size_t)NG * 1024 * 8;      // 548,864
static constexpr size_t OFF_MID  = REGA;
static constexpr size_t OFF_FG   = OFF_MID + 1945600;
static constexpr size_t OFF_BOX  = OFF_FG + 68608;
static constexpr size_t OFF_SBOX = OFF_BOX + 273664;
static constexpr size_t OFF_SAREA= OFF_SBOX + 273664;
static constexpr size_t OFF_CNT  = OFF_SAREA + 68608;
static constexpr size_t WS_NEED  = OFF_CNT + 68608;            // ~52.26 MB (unchanged)

__device__ __forceinline__ U64 rdlane64(U64 v, int l) {
    unsigned lo = (unsigned)__builtin_amdgcn_readlane((int)(unsigned)(v & 0xffffffffull), l);
    unsigned hi = (unsigned)__builtin_amdgcn_readlane((int)(unsigned)(v >> 32), l);
    return ((U64)hi << 32) | (U64)lo;
}

__device__ __forceinline__ U64 vmaskw(int wg) {
    int rem = NBOX - wg * 64;
    if (rem >= 64) return ~0ull;
    if (rem <= 0) return 0ull;
    return (1ull << rem) - 1ull;
}

// ---------------- kernels ----------------

__global__ __launch_bounds__(256) void k_sentinel(float* out, int n) {
    int i = blockIdx.x * 256 + threadIdx.x;
    if (i < n) out[i] = 1.2345678e8f;
}

// feature_map [CIN][H][W] -> in_tT [CIN][TPITCH] (padded image rows; memset first)
__global__ __launch_bounds__(256) void k_in_t(const float* __restrict__ fm, float* __restrict__ in_tT) {
    int idx = blockIdx.x * 256 + threadIdx.x;
    if (idx >= CIN * (H * W)) return;
    int ci = idx / (H * W), hw = idx - ci * (H * W);
    int h = hw / W, w = hw - h * W;
    in_tT[(size_t)ci * TPITCH + (h + 1) * WP + 1 + w] = fm[idx];
}

// conv_w [CMID][CIN][3][3] -> w2 [y(8)][sub(4)][ci(2048)][k(9)][c(8)]
__global__ __launch_bounds__(256) void k_w_t(const float* __restrict__ cw, float* __restrict__ w2) {
    int idx = blockIdx.x * 256 + threadIdx.x;
    if (idx >= CMID * CIN * 9) return;
    int co = idx / (CIN * 9);
    int rem = idx - co * (CIN * 9);
    int ci = rem / 9, k = rem - ci * 9;
    w2[((size_t)(co >> 3) * CIN + ci) * 72 + k * 8 + (co & 7)] = cw[idx];
}

// 3x3 conv, split-K. grid 896 = 16 qtiles of 128 x 8 cout-groups x 7 z
// (XCD-swizzled, z-major). Lane L owns q in {q0+L, q0+64+L}; scalar stride-1
// LDS reads (proven conflict-free, 0 conflicts measured round 16).
__global__ __launch_bounds__(256, 2) void k_conv(const float* __restrict__ in_tT,
                                                 const float* __restrict__ w2,
                                                 float* __restrict__ partial) {
    __shared__ float s_in[16 * SROW];    // 16 ci x 244 floats (15.6 KB)
    int t = threadIdx.x;
    int lane = t & 63;
    int sub = __builtin_amdgcn_readfirstlane(t >> 6);   // wave-uniform SGPR

    int raw = blockIdx.x;
    int xcd = raw & 7, i0 = raw >> 3;
    int L = xcd * 112 + i0;          // 896 = 8*112, bijective
    int z = L >> 7;                  // 7 z-slices (128 blocks each)
    int r0 = L & 127;
    int by = r0 >> 4, bx = r0 & 15;
    int q0 = bx * QTILE;
    int cout0 = by * 32;
    int cin0 = (z <= 1) ? 304 * z : 608 + 288 * (z - 2);   // 304,304,288x5
    int cin1 = cin0 + ((z <= 1) ? 304 : 288);

    float acc[2][8];
#pragma unroll
    for (int j = 0; j < 2; ++j)
#pragma unroll
        for (int c = 0; c < 8; ++c) acc[j][c] = 0.f;

    const float* wbase = w2 + (size_t)(by * 4 + sub) * CIN * 72;

    for (int c0 = cin0; c0 < cin1; c0 += 16) {
        // stage 16 ci rows: 61 quads each covering q in [q0-56, q0+187]
        for (int idx = t; idx < 16 * 61; idx += 256) {
            int r = idx / 61, j = idx - r * 61;
            int qf = q0 - 56 + 4 * j;
            float4 v = make_float4(0.f, 0.f, 0.f, 0.f);
            if (qf >= 0 && qf <= 2080)
                v = *reinterpret_cast<const float4*>(in_tT + (size_t)(c0 + r) * TPITCH + qf);
            *reinterpret_cast<float4*>(s_in + r * SROW + 4 * j) = v;
        }
        __syncthreads();
#pragma unroll 1
        for (int r = 0; r < 16; ++r) {
            const float* si = s_in + r * SROW + lane + 56;
            const float4* w4 = reinterpret_cast<const float4*>(wbase + (size_t)(c0 + r) * 72);
#pragma unroll
            for (int k = 0; k < 9; ++k) {
                const int DQ[9] = {-53, -52, -51, -1, 0, 1, 51, 52, 53};
                float iv0 = si[DQ[k]];
                float iv1 = si[DQ[k] + 64];
                float4 wa = w4[k * 2], wb = w4[k * 2 + 1];
                acc[0][0] += iv0 * wa.x; acc[0][1] += iv0 * wa.y;
                acc[0][2] += iv0 * wa.z; acc[0][3] += iv0 * wa.w;
                acc[0][4] += iv0 * wb.x; acc[0][5] += iv0 * wb.y;
                acc[0][6] += iv0 * wb.z; acc[0][7] += iv0 * wb.w;
                acc[1][0] += iv1 * wa.x; acc[1][1] += iv1 * wa.y;
                acc[1][2] += iv1 * wa.z; acc[1][3] += iv1 * wa.w;
                acc[1][4] += iv1 * wb.x; acc[1][5] += iv1 * wb.y;
                acc[1][6] += iv1 * wb.z; acc[1][7] += iv1 * wb.w;
            }
        }
        __syncthreads();
    }
    float* part = partial + (size_t)z * P * CMID;
#pragma unroll
    for (int jj = 0; jj < 2; ++jj) {
        int q = q0 + lane + 64 * jj;
        if (q < QP) {
            int hp = q / WP, wp_ = q - hp * WP;
            if (hp >= 1 && hp <= H && wp_ >= 1 && wp_ <= W) {
                int p = (hp - 1) * W + (wp_ - 1);
                float* dst = part + (size_t)p * CMID + cout0 + sub * 8;
                float4* d4 = reinterpret_cast<float4*>(dst);
                d4[0] = make_float4(acc[jj][0], acc[jj][1], acc[jj][2], acc[jj][3]);
                d4[1] = make_float4(acc[jj][4], acc[jj][5], acc[jj][6], acc[jj][7]);
            }
        }
    }
}

// sum partials + bias + relu -> mid [P][CMID]
__global__ __launch_bounds__(256) void k_reduce(const float* __restrict__ partial,
                                                const float* __restrict__ bias,
                                                float* __restrict__ mid) {
    int p = blockIdx.x, c = threadIdx.x;
    float s = bias[c];
    for (int ks = 0; ks < KS; ++ks) s += partial[(size_t)ks * P * CMID + (size_t)p * CMID + c];
    mid[(size_t)p * CMID + c] = fmaxf(s, 0.f);
}

// 1x1 heads + softmax + anchors + loc2bbox + clip. 16 positions per block (4 reps).
__global__ __launch_bounds__(256) void k_heads(const float* __restrict__ mid,
                                               const float* __restrict__ score_w,
                                               const float* __restrict__ score_b,
                                               const float* __restrict__ loc_w,
                                               const float* __restrict__ loc_b,
                                               float* __restrict__ score_out,
                                               float* __restrict__ loc_out,
                                               float* __restrict__ anch_out,
                                               float* __restrict__ fg,
                                               float* __restrict__ boxes) {
    __shared__ float wl[256][56];
    __shared__ float bias[56];
    __shared__ float dots[4][64];
    int t = threadIdx.x;
    for (int idx = t; idx < 18 * 256; idx += 256) {
        int c = idx >> 8, i = idx & 255;
        wl[i][c] = score_w[idx];
    }
    for (int idx = t; idx < 36 * 256; idx += 256) {
        int c = idx >> 8, i = idx & 255;
        wl[i][18 + c] = loc_w[idx];
    }
    if (t < 18) bias[t] = score_b[t];
    else if (t < 54) bias[t] = loc_b[t - 18];
    __syncthreads();

    int pl = t >> 6, c = t & 63;
    for (int rep = 0; rep < 4; ++rep) {
        int p = blockIdx.x * 16 + rep * 4 + pl;
        if (c < 54 && p < P) {
            float d = bias[c];
            const float4* mp = reinterpret_cast<const float4*>(mid + (size_t)p * CMID);
            for (int i4 = 0; i4 < 64; ++i4) {
                float4 m4 = mp[i4];
                int i = i4 * 4;
                d += m4.x * wl[i][c] + m4.y * wl[i + 1][c] + m4.z * wl[i + 2][c] + m4.w * wl[i + 3][c];
            }
            dots[pl][c] = d;
        }
        __syncthreads();
        if (c < NA && p < P) {
            int a = c;
            int idx = p * NA + a;
            float l0 = dots[pl][2 * a], l1 = dots[pl][2 * a + 1];
            float mx = fmaxf(l0, l1);
            float e0 = expf(l0 - mx), e1 = expf(l1 - mx);
            float den = e0 + e1;
            float s0 = e0 / den, s1 = e1 / den;
            score_out[(size_t)idx * 2 + 0] = s0;
            score_out[(size_t)idx * 2 + 1] = s1;
            fg[idx] = s1;
            float dx = dots[pl][18 + 4 * a + 0];
            float dy = dots[pl][18 + 4 * a + 1];
            float dw = dots[pl][18 + 4 * a + 2];
            float dh = dots[pl][18 + 4 * a + 3];
            loc_out[(size_t)idx * 4 + 0] = dx;
            loc_out[(size_t)idx * 4 + 1] = dy;
            loc_out[(size_t)idx * 4 + 2] = dw;
            loc_out[(size_t)idx * 4 + 3] = dh;
            int hh = p / W, ww = p % W;
            const double scales[3] = {8.0, 16.0, 32.0};
            const double ratios[3] = {0.5, 1.0, 2.0};
            double s = scales[a / 3], r = ratios[a % 3];
            double wb2 = 16.0 * s * sqrt(r);
            double hb = wb2 / r;
            double xmin = 8.0 - wb2 / 2.0, ymin = 8.0 - hb / 2.0;
            float b0 = (float)xmin, b1 = (float)ymin;
            float b2 = (float)(xmin + wb2), b3 = (float)(ymin + hb);
            float gx = (float)(ww * 16), gy = (float)(hh * 16);
            float a0 = gx + b0, a1 = gy + b1, a2 = gx + b2, a3 = gy + b3;
            anch_out[(size_t)idx * 4 + 0] = a0;
            anch_out[(size_t)idx * 4 + 1] = a1;
            anch_out[(size_t)idx * 4 + 2] = a2;
            anch_out[(size_t)idx * 4 + 3] = a3;
            float aw = a2 - a0, ah = a3 - a1;
            float cx = a0 + 0.5f * aw, cy = a1 + 0.5f * ah;
            float ncx = dx * aw + cx, ncy = dy * ah + cy;
            float nw = expf(dw) * aw, nh = expf(dh) * ah;
            float x1 = ncx - 0.5f * nw, y1 = ncy - 0.5f * nh;
            float x2 = ncx + 0.5f * nw, y2 = ncy + 0.5f * nh;
            x1 = fminf(fmaxf(x1, 0.f), (float)(W * 16));
            x2 = fminf(fmaxf(x2, 0.f), (float)(W * 16));
            y1 = fminf(fmaxf(y1, 0.f), (float)(H * 16));
            y2 = fminf(fmaxf(y2, 0.f), (float)(H * 16));
            float4* bp = reinterpret_cast<float4*>(boxes);
            bp[idx] = make_float4(x1, y1, x2, y2);
        }
        __syncthreads();
    }
}

// partial stable-descending rank counts over a j-slice. grid (67, 8)
static constexpr int JSL = 2144;  // slice size (mult of 4)
__global__ __launch_bounds__(256) void k_rank_part(const float* __restrict__ fg,
                                                   int* __restrict__ cntb) {
    __shared__ float4 tile[256];
    int t = threadIdx.x;
    int i = blockIdx.x * 256 + t;
    int j0 = blockIdx.y * JSL;
    int j1 = min(NBOX, j0 + JSL);
    float my = (i < NBOX) ? fg[i] : 0.f;
    int cnt = 0;
    for (int base = j0; base < j1; base += 1024) {
        int j = base + t * 4;
        float4 v = make_float4(-3.4e38f, -3.4e38f, -3.4e38f, -3.4e38f);
        if (j + 3 < j1) {
            v = *reinterpret_cast<const float4*>(fg + j);
        } else {
            if (j < j1) v.x = fg[j];
            if (j + 1 < j1) v.y = fg[j + 1];
            if (j + 2 < j1) v.z = fg[j + 2];
            if (j + 3 < j1) v.w = fg[j + 3];
        }
        __syncthreads();
        tile[t] = v;
        __syncthreads();
        if (i < NBOX) {
            for (int u = 0; u < 256; ++u) {
                float4 s = tile[u];
                int jb = base + u * 4;
                cnt += (s.x > my) || (s.x == my && jb < i);
                cnt += (s.y > my) || (s.y == my && jb + 1 < i);
                cnt += (s.z > my) || (s.z == my && jb + 2 < i);
                cnt += (s.w > my) || (s.w == my && jb + 3 < i);
            }
        }
    }
    if (i < NBOX && cnt) atomicAdd(&cntb[i], cnt);
}

// scatter boxes to sorted order using rank counts
__global__ __launch_bounds__(256) void k_scatter(const int* __restrict__ cntb,
                                                 const float* __restrict__ boxes,
                                                 float* __restrict__ sboxes,
                                                 float* __restrict__ sarea) {
    int i = blockIdx.x * 256 + threadIdx.x;
    if (i >= NBOX) return;
    int c = cntb[i];
    float4 b = reinterpret_cast<const float4*>(boxes)[i];
    reinterpret_cast<float4*>(sboxes)[c] = b;
    sarea[c] = (b.z - b.x) * (b.w - b.y);
}

// NMS pair bitmask, row-major + diag 256-block bands (diagX memset 0 first).
__global__ __launch_bounds__(256) void k_maskfill(const float* __restrict__ sboxes,
                                                  const float* __restrict__ sarea,
                                                  U64* __restrict__ mask,
                                                  U64* __restrict__ diagX) {
    int w = blockIdx.y;
    int i0 = blockIdx.x * 256;
    if (w < (i0 >> 6)) return;
    __shared__ float4 sb[64];
    __shared__ float sa[64];
    int t = threadIdx.x;
    if (t < 64) {
        int j = w * 64 + t;
        if (j < NBOX) {
            sb[t] = reinterpret_cast<const float4*>(sboxes)[j];
            sa[t] = sarea[j];
        } else {
            sb[t] = make_float4(0.f, 0.f, 0.f, 0.f);
            sa[t] = 0.f;
        }
    }
    __syncthreads();
    int i = i0 + t;
    if (i >= NBOX || w < (i >> 6)) return;
    float4 bi = reinterpret_cast<const float4*>(sboxes)[i];
    float ai = sarea[i];
    U64 word = 0;
#pragma unroll 4
    for (int jb = 0; jb < 64; ++jb) {
        int j = w * 64 + jb;
        float4 bj = sb[jb];
        float xx1 = fmaxf(bi.x, bj.x), yy1 = fmaxf(bi.y, bj.y);
        float xx2 = fminf(bi.z, bj.z), yy2 = fminf(bi.w, bj.w);
        float inter = fmaxf(xx2 - xx1, 0.f) * fmaxf(yy2 - yy1, 0.f);
        float iou = inter / (ai + sa[jb] - inter);
        word |= ((U64)((iou > NMS_T) && (j > i))) << jb;
    }
    mask[(size_t)i * MSTRIDE + w] = word;
    int gi = i >> 8;
    int wl = w - gi * 4;
    if (wl >= 0 && wl < 4)
        diagX[(size_t)gi * 1024 + wl * 256 + (i & 255)] = word;
}

// ---- sweep v9: single wave, asm-pinned pipeline (round-12, unchanged).
#define GLOAD64(dst, addr) \
    asm volatile("global_load_dwordx2 %0, %1, off" : "=v"(dst) : "v"(addr))

#define VWAIT0() do { asm volatile("s_waitcnt vmcnt(0)" ::: "memory"); \
                      __builtin_amdgcn_sched_barrier(0); } while (0)

#define DVARS(P) U64 P##00, P##01, P##02, P##03, P##10, P##11, P##12, P##13, \
                     P##20, P##21, P##22, P##23, P##30, P##31, P##32, P##33

#define DISSUE(P, G) do { \
    const U64* _dp = diagX + (size_t)(G) * 1024 + lane; \
    GLOAD64(P##00, _dp +   0); GLOAD64(P##01, _dp +  64); GLOAD64(P##02, _dp + 128); GLOAD64(P##03, _dp + 192); \
    GLOAD64(P##10, _dp + 256); GLOAD64(P##11, _dp + 320); GLOAD64(P##12, _dp + 384); GLOAD64(P##13, _dp + 448); \
    GLOAD64(P##20, _dp + 512); GLOAD64(P##21, _dp + 576); GLOAD64(P##22, _dp + 640); GLOAD64(P##23, _dp + 704); \
    GLOAD64(P##30, _dp + 768); GLOAD64(P##31, _dp + 832); GLOAD64(P##32, _dp + 896); GLOAD64(P##33, _dp + 960); \
} while (0)

#define ZEROD(P) do { \
    P##00 = P##01 = P##02 = P##03 = P##10 = P##11 = P##12 = P##13 = 0; \
    P##20 = P##21 = P##22 = P##23 = P##30 = P##31 = P##32 = P##33 = 0; \
} while (0)

#define POPR(R) \
    int R; \
    do { \
        if (kk0) { int _i = (int)__builtin_ctzll(kk0); kk0 &= kk0 - 1; R = _i; } \
        else if (kk1) { int _i = (int)__builtin_ctzll(kk1); kk1 &= kk1 - 1; R = 64 + _i; } \
        else if (kk2) { int _i = (int)__builtin_ctzll(kk2); kk2 &= kk2 - 1; R = 128 + _i; } \
        else if (kk3) { int _i = (int)__builtin_ctzll(kk3); kk3 &= kk3 - 1; R = 192 + _i; } \
        else R = -1; \
    } while (0)

__global__ __launch_bounds__(64, 1) void k_sweep(const U64* __restrict__ mask,
                                                 const U64* __restrict__ diagX,
                                                 const float* __restrict__ sboxes,
                                                 float* __restrict__ rois_out,
                                                 float* __restrict__ keep_out) {
    int lane = threadIdx.x;
    U64 m0 = 0, m1 = 0, m2 = 0, m3 = 0, m4 = 0;
    unsigned base = 0;
    DVARS(c);
    DVARS(n);
    DISSUE(c, 0);
    VWAIT0();

    for (int g = 0; g < NG; ++g) {
        if (g + 1 < NG) { DISSUE(n, g + 1); } else { ZEROD(n); }

        const int gbase = g * 256;
        int rsel = g >> 4;
        U64 msel = (rsel == 0) ? m0 : (rsel == 1) ? m1 : (rsel == 2) ? m2 : (rsel == 3) ? m3 : m4;
        int lb = (g * 4) & 63;
        U64 mc0 = rdlane64(msel, lb), mc1 = rdlane64(msel, lb + 1);
        U64 mc2 = rdlane64(msel, lb + 2), mc3 = rdlane64(msel, lb + 3);
        U64 ns0 = ~mc0 & vmaskw(g * 4),     ns1 = ~mc1 & vmaskw(g * 4 + 1);
        U64 ns2 = ~mc2 & vmaskw(g * 4 + 2), ns3 = ~mc3 & vmaskw(g * 4 + 3);
        U64 k0 = 0, k1 = 0, k2 = 0, k3 = 0;
        while (ns0) {
            int i = (int)__builtin_ctzll(ns0);
            k0 |= 1ull << i;
            ns0 &= ~(rdlane64(c00, i) | (1ull << i));
            ns1 &= ~rdlane64(c10, i);
            ns2 &= ~rdlane64(c20, i);
            ns3 &= ~rdlane64(c30, i);
        }
        while (ns1) {
            int i = (int)__builtin_ctzll(ns1);
            k1 |= 1ull << i;
            ns1 &= ~(rdlane64(c11, i) | (1ull << i));
            ns2 &= ~rdlane64(c21, i);
            ns3 &= ~rdlane64(c31, i);
        }
        while (ns2) {
            int i = (int)__builtin_ctzll(ns2);
            k2 |= 1ull << i;
            ns2 &= ~(rdlane64(c22, i) | (1ull << i));
            ns3 &= ~rdlane64(c32, i);
        }
        while (ns3) {
            int i = (int)__builtin_ctzll(ns3);
            k3 |= 1ull << i;
            ns3 &= ~(rdlane64(c33, i) | (1ull << i));
        }
        unsigned p0 = (unsigned)__popcll(k0), p1 = (unsigned)__popcll(k1);
        unsigned p2 = (unsigned)__popcll(k2), p3 = (unsigned)__popcll(k3);
        U64 lmask = (1ull << lane) - 1ull;
        if ((k0 >> lane) & 1) {
            unsigned dst = base + (unsigned)__popcll(k0 & lmask);
            reinterpret_cast<float4*>(rois_out)[dst] = reinterpret_cast<const float4*>(sboxes)[gbase + lane];
            keep_out[dst] = 1.0f;
        }
        if ((k1 >> lane) & 1) {
            unsigned dst = base + p0 + (unsigned)__popcll(k1 & lmask);
            reinterpret_cast<float4*>(rois_out)[dst] = reinterpret_cast<const float4*>(sboxes)[gbase + 64 + lane];
            keep_out[dst] = 1.0f;
        }
        if ((k2 >> lane) & 1) {
            unsigned dst = base + p0 + p1 + (unsigned)__popcll(k2 & lmask);
            reinterpret_cast<float4*>(rois_out)[dst] = reinterpret_cast<const float4*>(sboxes)[gbase + 128 + lane];
            keep_out[dst] = 1.0f;
        }
        if ((k3 >> lane) & 1) {
            unsigned dst = base + p0 + p1 + p2 + (unsigned)__popcll(k3 & lmask);
            reinterpret_cast<float4*>(rois_out)[dst] = reinterpret_cast<const float4*>(sboxes)[gbase + 192 + lane];
            keep_out[dst] = 1.0f;
        }
        base += p0 + p1 + p2 + p3;

        const int wmin = g * 4 + 4;
        const bool gw0 = (lane >= wmin);
        const bool gw1 = (64 + lane >= wmin);
        const bool gw2 = (128 + lane >= wmin);
        const bool gw3 = (192 + lane >= wmin);
        const bool gw4 = (256 + lane >= wmin) && (256 + lane < NW);
        U64 kk0 = k0, kk1 = k1, kk2 = k2, kk3 = k3;
        bool any = (kk0 | kk1 | kk2 | kk3) != 0;
        while (kk0 | kk1 | kk2 | kk3) {
            POPR(ra); POPR(rb); POPR(rc); POPR(rd);
            if (rb < 0) rb = ra;
            if (rc < 0) rc = ra;
            if (rd < 0) rd = ra;
            const U64* qa = mask + (size_t)(gbase + ra) * MSTRIDE + lane;
            const U64* qb = mask + (size_t)(gbase + rb) * MSTRIDE + lane;
            const U64* qc = mask + (size_t)(gbase + rc) * MSTRIDE + lane;
            const U64* qd = mask + (size_t)(gbase + rd) * MSTRIDE + lane;
            U64 va0, va1, va2, va3, va4, vb0, vb1, vb2, vb3, vb4;
            U64 vc0, vc1, vc2, vc3, vc4, vd0, vd1, vd2, vd3, vd4;
            GLOAD64(va0, qa);       GLOAD64(va1, qa + 64);  GLOAD64(va2, qa + 128);
            GLOAD64(va3, qa + 192); GLOAD64(va4, qa + 256);
            GLOAD64(vb0, qb);       GLOAD64(vb1, qb + 64);  GLOAD64(vb2, qb + 128);
            GLOAD64(vb3, qb + 192); GLOAD64(vb4, qb + 256);
            GLOAD64(vc0, qc);       GLOAD64(vc1, qc + 64);  GLOAD64(vc2, qc + 128);
            GLOAD64(vc3, qc + 192); GLOAD64(vc4, qc + 256);
            GLOAD64(vd0, qd);       GLOAD64(vd1, qd + 64);  GLOAD64(vd2, qd + 128);
            GLOAD64(vd3, qd + 192); GLOAD64(vd4, qd + 256);
            VWAIT0();
            if (gw0) m0 |= va0 | vb0 | vc0 | vd0;
            if (gw1) m1 |= va1 | vb1 | vc1 | vd1;
            if (gw2) m2 |= va2 | vb2 | vc2 | vd2;
            if (gw3) m3 |= va3 | vb3 | vc3 | vd3;
            if (gw4) m4 |= va4 | vb4 | vc4 | vd4;
        }
        if (!any) VWAIT0();

        c00 = n00; c01 = n01; c02 = n02; c03 = n03;
        c10 = n10; c11 = n11; c12 = n12; c13 = n13;
        c20 = n20; c21 = n21; c22 = n22; c23 = n23;
        c30 = n30; c31 = n31; c32 = n32; c33 = n33;
    }
}

// ---------------- launch ----------------
extern "C" void kernel_launch(void* const* d_in, const int* in_sizes, int n_in,
                              void* d_out, int out_size, void* d_ws, size_t ws_size,
                              hipStream_t stream) {
    const float* fm      = (const float*)d_in[0];
    const float* conv_w  = (const float*)d_in[2];
    const float* conv_b  = (const float*)d_in[3];
    const float* score_w = (const float*)d_in[4];
    const float* score_b = (const float*)d_in[5];
    const float* loc_w   = (const float*)d_in[6];
    const float* loc_b   = (const float*)d_in[7];

    float* out = (float*)d_out;
    float* rois_out  = out;
    float* keep_out  = out + NBOX * 4;
    float* anch_out  = out + NBOX * 5;
    float* loc_out   = out + NBOX * 9;
    float* score_out = out + NBOX * 13;

    if (ws_size < WS_NEED) {
        k_sentinel<<<(out_size + 255) / 256, 256, 0, stream>>>(out, out_size);
        return;
    }

    char* ws = (char*)d_ws;
    float* in_tT   = (float*)(ws + OFF_INT);
    float* w2      = (float*)(ws + OFF_WT);
    float* partial = (float*)(ws + OFF_PART);
    U64*   mask    = (U64*)(ws + OFF_MASK);
    U64*   diagX   = (U64*)(ws + OFF_DIAG);
    float* mid     = (float*)(ws + OFF_MID);
    float* fg      = (float*)(ws + OFF_FG);
    float* boxes   = (float*)(ws + OFF_BOX);
    float* sboxes  = (float*)(ws + OFF_SBOX);
    float* sarea   = (float*)(ws + OFF_SAREA);
    int*   cntb    = (int*)(ws + OFF_CNT);

    hipMemsetAsync(in_tT, 0, SZ_INT, stream);
    k_in_t<<<(CIN * H * W + 255) / 256, 256, 0, stream>>>(fm, in_tT);
    k_w_t<<<(CMID * CIN * 9 + 255) / 256, 256, 0, stream>>>(conv_w, w2);
    k_conv<<<896, 256, 0, stream>>>(in_tT, w2, partial);
    k_reduce<<<P, 256, 0, stream>>>(partial, conv_b, mid);
    k_heads<<<(P + 15) / 16, 256, 0, stream>>>(mid, score_w, score_b, loc_w, loc_b,
                                               score_out, loc_out, anch_out, fg, boxes);
    hipMemsetAsync(cntb, 0, NBOX * 4, stream);
    k_rank_part<<<dim3((NBOX + 255) / 256, 8), 256, 0, stream>>>(fg, cntb);
    k_scatter<<<(NBOX + 255) / 256, 256, 0, stream>>>(cntb, boxes, sboxes, sarea);
    hipMemsetAsync(rois_out, 0, (size_t)NBOX * 5 * 4, stream);  // rois_out + keep
    hipMemsetAsync(diagX, 0, SZ_DIAG, stream);
    k_maskfill<<<dim3((NBOX + 255) / 256, NW), 256, 0, stream>>>(sboxes, sarea, mask, diagX);
    k_sweep<<<1, 64, 0, stream>>>(mask, diagX, sboxes, rois_out, keep_out);
}

// Round 20
// 727.992 us; speedup vs baseline: 1.1104x; 1.0330x over previous
//
#include <hip/hip_runtime.h>
#include <cstdint>

#define U64 unsigned long long

static constexpr int H = 38, W = 50, P = 1900;        // feature map
static constexpr int CIN = 2048, CMID = 256;
static constexpr int NA = 9, NBOX = 17100;            // 1900*9
static constexpr int HP = 40, WP = 52, QP = HP * WP;  // padded positions (2080)
static constexpr int TPITCH = 2084;                   // in_tT row pitch (floats), mult of 4
static constexpr int KS = 8;                          // split-K over cin (8 x 256)
static constexpr int NW = 268;                        // u64 words covering NBOX bits
static constexpr int MSTRIDE = 272;                   // mask row stride (words)
static constexpr int NG = 67;                         // 256-box groups
static constexpr float NMS_T = 0.5f;
static constexpr int QTILE = 128;                     // proven optimum (299/277/336 for 256/128/64)
static constexpr int SROW = 244;                      // s_in row stride (floats)

// ---------------- ws layout (bytes) ----------------
static constexpr size_t SZ_INT  = (size_t)CIN * TPITCH * 4;   // 17,072,128
static constexpr size_t SZ_WT   = (size_t)9 * CIN * CMID * 4; // 18,874,368
static constexpr size_t SZ_PART = (size_t)KS * P * CMID * 4;  // 15,564,800
static constexpr size_t OFF_INT  = 0;
static constexpr size_t OFF_WT   = OFF_INT + SZ_INT;
static constexpr size_t OFF_PART = OFF_WT + SZ_WT;            // 35,946,496
static constexpr size_t REGA     = OFF_PART + SZ_PART;        // 51,511,296
// region A overlay (dead after k_reduce): mask + diag 256-blocks
static constexpr size_t OFF_MASK = 0;                          // mask [NBOX][MSTRIDE] (37.2 MB)
static constexpr size_t SZ_MASK  = (size_t)NBOX * MSTRIDE * 8; // 37,209,600
static constexpr size_t OFF_DIAG = SZ_MASK;                    // diagX [67][4][4][64] u64 (549 KB)
static constexpr size_t SZ_DIAG  = (size_t)NG * 1024 * 8;      // 548,864
static constexpr size_t OFF_MID  = OFF_PART;                   // mid ALIASES partial slice 0
                                                               // (k_reduce reads-then-writes per elem;
                                                               //  mid dead before maskfill overlay)
static constexpr size_t OFF_FG   = REGA;                       // 51,511,296 (same as before)
static constexpr size_t OFF_BOX  = OFF_FG + 68608;
static constexpr size_t OFF_SBOX = OFF_BOX + 273664;
static constexpr size_t OFF_SAREA= OFF_SBOX + 273664;
static constexpr size_t OFF_CNT  = OFF_SAREA + 68608;
static constexpr size_t WS_NEED  = OFF_CNT + 68608;            // 52,264,448 (unchanged)

__device__ __forceinline__ U64 rdlane64(U64 v, int l) {
    unsigned lo = (unsigned)__builtin_amdgcn_readlane((int)(unsigned)(v & 0xffffffffull), l);
    unsigned hi = (unsigned)__builtin_amdgcn_readlane((int)(unsigned)(v >> 32), l);
    return ((U64)hi << 32) | (U64)lo;
}

__device__ __forceinline__ U64 vmaskw(int wg) {
    int rem = NBOX - wg * 64;
    if (rem >= 64) return ~0ull;
    if (rem <= 0) return 0ull;
    return (1ull << rem) - 1ull;
}

// ---------------- kernels ----------------

__global__ __launch_bounds__(256) void k_sentinel(float* out, int n) {
    int i = blockIdx.x * 256 + threadIdx.x;
    if (i < n) out[i] = 1.2345678e8f;
}

// feature_map [CIN][H][W] -> in_tT [CIN][TPITCH] (padded image rows; memset first)
__global__ __launch_bounds__(256) void k_in_t(const float* __restrict__ fm, float* __restrict__ in_tT) {
    int idx = blockIdx.x * 256 + threadIdx.x;
    if (idx >= CIN * (H * W)) return;
    int ci = idx / (H * W), hw = idx - ci * (H * W);
    int h = hw / W, w = hw - h * W;
    in_tT[(size_t)ci * TPITCH + (h + 1) * WP + 1 + w] = fm[idx];
}

// conv_w [CMID][CIN][3][3] -> w2 [y(8)][sub(4)][ci(2048)][k(9)][c(8)]
__global__ __launch_bounds__(256) void k_w_t(const float* __restrict__ cw, float* __restrict__ w2) {
    int idx = blockIdx.x * 256 + threadIdx.x;
    if (idx >= CMID * CIN * 9) return;
    int co = idx / (CIN * 9);
    int rem = idx - co * (CIN * 9);
    int ci = rem / 9, k = rem - ci * 9;
    w2[((size_t)(co >> 3) * CIN + ci) * 72 + k * 8 + (co & 7)] = cw[idx];
}

// 3x3 conv, split-K. grid 1024 = 16 qtiles of 128 x 8 cout-groups x 8 z
// (XCD-swizzled, z-major; exactly 4 blocks/CU). Lane L owns q in {q0+L, q0+64+L};
// scalar stride-1 LDS reads (proven conflict-free, 0 conflicts round 16/19).
// Inner loop byte-identical to round-19 passing build.
__global__ __launch_bounds__(256, 2) void k_conv(const float* __restrict__ in_tT,
                                                 const float* __restrict__ w2,
                                                 float* __restrict__ partial) {
    __shared__ float s_in[16 * SROW];    // 16 ci x 244 floats (15.6 KB)
    int t = threadIdx.x;
    int lane = t & 63;
    int sub = __builtin_amdgcn_readfirstlane(t >> 6);   // wave-uniform SGPR

    int raw = blockIdx.x;
    int xcd = raw & 7, i0 = raw >> 3;
    int L = xcd * 128 + i0;          // 1024 = 8*128, bijective
    int z = L >> 7;                  // 8 z-slices (128 blocks each)
    int r0 = L & 127;
    int by = r0 >> 4, bx = r0 & 15;
    int q0 = bx * QTILE;
    int cout0 = by * 32;
    int cin0 = z * 256;
    int cin1 = cin0 + 256;

    float acc[2][8];
#pragma unroll
    for (int j = 0; j < 2; ++j)
#pragma unroll
        for (int c = 0; c < 8; ++c) acc[j][c] = 0.f;

    const float* wbase = w2 + (size_t)(by * 4 + sub) * CIN * 72;

    for (int c0 = cin0; c0 < cin1; c0 += 16) {
        // stage 16 ci rows: 61 quads each covering q in [q0-56, q0+187]
        for (int idx = t; idx < 16 * 61; idx += 256) {
            int r = idx / 61, j = idx - r * 61;
            int qf = q0 - 56 + 4 * j;
            float4 v = make_float4(0.f, 0.f, 0.f, 0.f);
            if (qf >= 0 && qf <= 2080)
                v = *reinterpret_cast<const float4*>(in_tT + (size_t)(c0 + r) * TPITCH + qf);
            *reinterpret_cast<float4*>(s_in + r * SROW + 4 * j) = v;
        }
        __syncthreads();
#pragma unroll 1
        for (int r = 0; r < 16; ++r) {
            const float* si = s_in + r * SROW + lane + 56;
            const float4* w4 = reinterpret_cast<const float4*>(wbase + (size_t)(c0 + r) * 72);
#pragma unroll
            for (int k = 0; k < 9; ++k) {
                const int DQ[9] = {-53, -52, -51, -1, 0, 1, 51, 52, 53};
                float iv0 = si[DQ[k]];
                float iv1 = si[DQ[k] + 64];
                float4 wa = w4[k * 2], wb = w4[k * 2 + 1];
                acc[0][0] += iv0 * wa.x; acc[0][1] += iv0 * wa.y;
                acc[0][2] += iv0 * wa.z; acc[0][3] += iv0 * wa.w;
                acc[0][4] += iv0 * wb.x; acc[0][5] += iv0 * wb.y;
                acc[0][6] += iv0 * wb.z; acc[0][7] += iv0 * wb.w;
                acc[1][0] += iv1 * wa.x; acc[1][1] += iv1 * wa.y;
                acc[1][2] += iv1 * wa.z; acc[1][3] += iv1 * wa.w;
                acc[1][4] += iv1 * wb.x; acc[1][5] += iv1 * wb.y;
                acc[1][6] += iv1 * wb.z; acc[1][7] += iv1 * wb.w;
            }
        }
        __syncthreads();
    }
    float* part = partial + (size_t)z * P * CMID;
#pragma unroll
    for (int jj = 0; jj < 2; ++jj) {
        int q = q0 + lane + 64 * jj;
        if (q < QP) {
            int hp = q / WP, wp_ = q - hp * WP;
            if (hp >= 1 && hp <= H && wp_ >= 1 && wp_ <= W) {
                int p = (hp - 1) * W + (wp_ - 1);
                float* dst = part + (size_t)p * CMID + cout0 + sub * 8;
                float4* d4 = reinterpret_cast<float4*>(dst);
                d4[0] = make_float4(acc[jj][0], acc[jj][1], acc[jj][2], acc[jj][3]);
                d4[1] = make_float4(acc[jj][4], acc[jj][5], acc[jj][6], acc[jj][7]);
            }
        }
    }
}

// sum partials + bias + relu -> mid [P][CMID]  (mid aliases partial slice 0;
// each thread reads all its slices before writing its own element)
__global__ __launch_bounds__(256) void k_reduce(const float* __restrict__ partial,
                                                const float* __restrict__ bias,
                                                float* __restrict__ mid) {
    int p = blockIdx.x, c = threadIdx.x;
    float s = bias[c];
    for (int ks = 0; ks < KS; ++ks) s += partial[(size_t)ks * P * CMID + (size_t)p * CMID + c];
    mid[(size_t)p * CMID + c] = fmaxf(s, 0.f);
}

// 1x1 heads + softmax + anchors + loc2bbox + clip. 16 positions per block (4 reps).
__global__ __launch_bounds__(256) void k_heads(const float* __restrict__ mid,
                                               const float* __restrict__ score_w,
                                               const float* __restrict__ score_b,
                                               const float* __restrict__ loc_w,
                                               const float* __restrict__ loc_b,
                                               float* __restrict__ score_out,
                                               float* __restrict__ loc_out,
                                               float* __restrict__ anch_out,
                                               float* __restrict__ fg,
                                               float* __restrict__ boxes) {
    __shared__ float wl[256][56];
    __shared__ float bias[56];
    __shared__ float dots[4][64];
    int t = threadIdx.x;
    for (int idx = t; idx < 18 * 256; idx += 256) {
        int c = idx >> 8, i = idx & 255;
        wl[i][c] = score_w[idx];
    }
    for (int idx = t; idx < 36 * 256; idx += 256) {
        int c = idx >> 8, i = idx & 255;
        wl[i][18 + c] = loc_w[idx];
    }
    if (t < 18) bias[t] = score_b[t];
    else if (t < 54) bias[t] = loc_b[t - 18];
    __syncthreads();

    int pl = t >> 6, c = t & 63;
    for (int rep = 0; rep < 4; ++rep) {
        int p = blockIdx.x * 16 + rep * 4 + pl;
        if (c < 54 && p < P) {
            float d = bias[c];
            const float4* mp = reinterpret_cast<const float4*>(mid + (size_t)p * CMID);
            for (int i4 = 0; i4 < 64; ++i4) {
                float4 m4 = mp[i4];
                int i = i4 * 4;
                d += m4.x * wl[i][c] + m4.y * wl[i + 1][c] + m4.z * wl[i + 2][c] + m4.w * wl[i + 3][c];
            }
            dots[pl][c] = d;
        }
        __syncthreads();
        if (c < NA && p < P) {
            int a = c;
            int idx = p * NA + a;
            float l0 = dots[pl][2 * a], l1 = dots[pl][2 * a + 1];
            float mx = fmaxf(l0, l1);
            float e0 = expf(l0 - mx), e1 = expf(l1 - mx);
            float den = e0 + e1;
            float s0 = e0 / den, s1 = e1 / den;
            score_out[(size_t)idx * 2 + 0] = s0;
            score_out[(size_t)idx * 2 + 1] = s1;
            fg[idx] = s1;
            float dx = dots[pl][18 + 4 * a + 0];
            float dy = dots[pl][18 + 4 * a + 1];
            float dw = dots[pl][18 + 4 * a + 2];
            float dh = dots[pl][18 + 4 * a + 3];
            loc_out[(size_t)idx * 4 + 0] = dx;
            loc_out[(size_t)idx * 4 + 1] = dy;
            loc_out[(size_t)idx * 4 + 2] = dw;
            loc_out[(size_t)idx * 4 + 3] = dh;
            int hh = p / W, ww = p % W;
            const double scales[3] = {8.0, 16.0, 32.0};
            const double ratios[3] = {0.5, 1.0, 2.0};
            double s = scales[a / 3], r = ratios[a % 3];
            double wb2 = 16.0 * s * sqrt(r);
            double hb = wb2 / r;
            double xmin = 8.0 - wb2 / 2.0, ymin = 8.0 - hb / 2.0;
            float b0 = (float)xmin, b1 = (float)ymin;
            float b2 = (float)(xmin + wb2), b3 = (float)(ymin + hb);
            float gx = (float)(ww * 16), gy = (float)(hh * 16);
            float a0 = gx + b0, a1 = gy + b1, a2 = gx + b2, a3 = gy + b3;
            anch_out[(size_t)idx * 4 + 0] = a0;
            anch_out[(size_t)idx * 4 + 1] = a1;
            anch_out[(size_t)idx * 4 + 2] = a2;
            anch_out[(size_t)idx * 4 + 3] = a3;
            float aw = a2 - a0, ah = a3 - a1;
            float cx = a0 + 0.5f * aw, cy = a1 + 0.5f * ah;
            float ncx = dx * aw + cx, ncy = dy * ah + cy;
            float nw = expf(dw) * aw, nh = expf(dh) * ah;
            float x1 = ncx - 0.5f * nw, y1 = ncy - 0.5f * nh;
            float x2 = ncx + 0.5f * nw, y2 = ncy + 0.5f * nh;
            x1 = fminf(fmaxf(x1, 0.f), (float)(W * 16));
            x2 = fminf(fmaxf(x2, 0.f), (float)(W * 16));
            y1 = fminf(fmaxf(y1, 0.f), (float)(H * 16));
            y2 = fminf(fmaxf(y2, 0.f), (float)(H * 16));
            float4* bp = reinterpret_cast<float4*>(boxes);
            bp[idx] = make_float4(x1, y1, x2, y2);
        }
        __syncthreads();
    }
}

// partial stable-descending rank counts over a j-slice. grid (67, 8)
static constexpr int JSL = 2144;  // slice size (mult of 4)
__global__ __launch_bounds__(256) void k_rank_part(const float* __restrict__ fg,
                                                   int* __restrict__ cntb) {
    __shared__ float4 tile[256];
    int t = threadIdx.x;
    int i = blockIdx.x * 256 + t;
    int j0 = blockIdx.y * JSL;
    int j1 = min(NBOX, j0 + JSL);
    float my = (i < NBOX) ? fg[i] : 0.f;
    int cnt = 0;
    for (int base = j0; base < j1; base += 1024) {
        int j = base + t * 4;
        float4 v = make_float4(-3.4e38f, -3.4e38f, -3.4e38f, -3.4e38f);
        if (j + 3 < j1) {
            v = *reinterpret_cast<const float4*>(fg + j);
        } else {
            if (j < j1) v.x = fg[j];
            if (j + 1 < j1) v.y = fg[j + 1];
            if (j + 2 < j1) v.z = fg[j + 2];
            if (j + 3 < j1) v.w = fg[j + 3];
        }
        __syncthreads();
        tile[t] = v;
        __syncthreads();
        if (i < NBOX) {
            for (int u = 0; u < 256; ++u) {
                float4 s = tile[u];
                int jb = base + u * 4;
                cnt += (s.x > my) || (s.x == my && jb < i);
                cnt += (s.y > my) || (s.y == my && jb + 1 < i);
                cnt += (s.z > my) || (s.z == my && jb + 2 < i);
                cnt += (s.w > my) || (s.w == my && jb + 3 < i);
            }
        }
    }
    if (i < NBOX && cnt) atomicAdd(&cntb[i], cnt);
}

// scatter boxes to sorted order using rank counts
__global__ __launch_bounds__(256) void k_scatter(const int* __restrict__ cntb,
                                                 const float* __restrict__ boxes,
                                                 float* __restrict__ sboxes,
                                                 float* __restrict__ sarea) {
    int i = blockIdx.x * 256 + threadIdx.x;
    if (i >= NBOX) return;
    int c = cntb[i];
    float4 b = reinterpret_cast<const float4*>(boxes)[i];
    reinterpret_cast<float4*>(sboxes)[c] = b;
    sarea[c] = (b.z - b.x) * (b.w - b.y);
}

// NMS pair bitmask, row-major + diag 256-block bands (diagX memset 0 first).
__global__ __launch_bounds__(256) void k_maskfill(const float* __restrict__ sboxes,
                                                  const float* __restrict__ sarea,
                                                  U64* __restrict__ mask,
                                                  U64* __restrict__ diagX) {
    int w = blockIdx.y;
    int i0 = blockIdx.x * 256;
    if (w < (i0 >> 6)) return;
    __shared__ float4 sb[64];
    __shared__ float sa[64];
    int t = threadIdx.x;
    if (t < 64) {
        int j = w * 64 + t;
        if (j < NBOX) {
            sb[t] = reinterpret_cast<const float4*>(sboxes)[j];
            sa[t] = sarea[j];
        } else {
            sb[t] = make_float4(0.f, 0.f, 0.f, 0.f);
            sa[t] = 0.f;
        }
    }
    __syncthreads();
    int i = i0 + t;
    if (i >= NBOX || w < (i >> 6)) return;
    float4 bi = reinterpret_cast<const float4*>(sboxes)[i];
    float ai = sarea[i];
    U64 word = 0;
#pragma unroll 4
    for (int jb = 0; jb < 64; ++jb) {
        int j = w * 64 + jb;
        float4 bj = sb[jb];
        float xx1 = fmaxf(bi.x, bj.x), yy1 = fmaxf(bi.y, bj.y);
        float xx2 = fminf(bi.z, bj.z), yy2 = fminf(bi.w, bj.w);
        float inter = fmaxf(xx2 - xx1, 0.f) * fmaxf(yy2 - yy1, 0.f);
        float iou = inter / (ai + sa[jb] - inter);
        word |= ((U64)((iou > NMS_T) && (j > i))) << jb;
    }
    mask[(size_t)i * MSTRIDE + w] = word;
    int gi = i >> 8;
    int wl = w - gi * 4;
    if (wl >= 0 && wl < 4)
        diagX[(size_t)gi * 1024 + wl * 256 + (i & 255)] = word;
}

// ---- sweep v9: single wave, asm-pinned pipeline (round-12, unchanged).
#define GLOAD64(dst, addr) \
    asm volatile("global_load_dwordx2 %0, %1, off" : "=v"(dst) : "v"(addr))

#define VWAIT0() do { asm volatile("s_waitcnt vmcnt(0)" ::: "memory"); \
                      __builtin_amdgcn_sched_barrier(0); } while (0)

#define DVARS(P) U64 P##00, P##01, P##02, P##03, P##10, P##11, P##12, P##13, \
                     P##20, P##21, P##22, P##23, P##30, P##31, P##32, P##33

#define DISSUE(P, G) do { \
    const U64* _dp = diagX + (size_t)(G) * 1024 + lane; \
    GLOAD64(P##00, _dp +   0); GLOAD64(P##01, _dp +  64); GLOAD64(P##02, _dp + 128); GLOAD64(P##03, _dp + 192); \
    GLOAD64(P##10, _dp + 256); GLOAD64(P##11, _dp + 320); GLOAD64(P##12, _dp + 384); GLOAD64(P##13, _dp + 448); \
    GLOAD64(P##20, _dp + 512); GLOAD64(P##21, _dp + 576); GLOAD64(P##22, _dp + 640); GLOAD64(P##23, _dp + 704); \
    GLOAD64(P##30, _dp + 768); GLOAD64(P##31, _dp + 832); GLOAD64(P##32, _dp + 896); GLOAD64(P##33, _dp + 960); \
} while (0)

#define ZEROD(P) do { \
    P##00 = P##01 = P##02 = P##03 = P##10 = P##11 = P##12 = P##13 = 0; \
    P##20 = P##21 = P##22 = P##23 = P##30 = P##31 = P##32 = P##33 = 0; \
} while (0)

#define POPR(R) \
    int R; \
    do { \
        if (kk0) { int _i = (int)__builtin_ctzll(kk0); kk0 &= kk0 - 1; R = _i; } \
        else if (kk1) { int _i = (int)__builtin_ctzll(kk1); kk1 &= kk1 - 1; R = 64 + _i; } \
        else if (kk2) { int _i = (int)__builtin_ctzll(kk2); kk2 &= kk2 - 1; R = 128 + _i; } \
        else if (kk3) { int _i = (int)__builtin_ctzll(kk3); kk3 &= kk3 - 1; R = 192 + _i; } \
        else R = -1; \
    } while (0)

__global__ __launch_bounds__(64, 1) void k_sweep(const U64* __restrict__ mask,
                                                 const U64* __restrict__ diagX,
                                                 const float* __restrict__ sboxes,
                                                 float* __restrict__ rois_out,
                                                 float* __restrict__ keep_out) {
    int lane = threadIdx.x;
    U64 m0 = 0, m1 = 0, m2 = 0, m3 = 0, m4 = 0;
    unsigned base = 0;
    DVARS(c);
    DVARS(n);
    DISSUE(c, 0);
    VWAIT0();

    for (int g = 0; g < NG; ++g) {
        if (g + 1 < NG) { DISSUE(n, g + 1); } else { ZEROD(n); }

        const int gbase = g * 256;
        int rsel = g >> 4;
        U64 msel = (rsel == 0) ? m0 : (rsel == 1) ? m1 : (rsel == 2) ? m2 : (rsel == 3) ? m3 : m4;
        int lb = (g * 4) & 63;
        U64 mc0 = rdlane64(msel, lb), mc1 = rdlane64(msel, lb + 1);
        U64 mc2 = rdlane64(msel, lb + 2), mc3 = rdlane64(msel, lb + 3);
        U64 ns0 = ~mc0 & vmaskw(g * 4),     ns1 = ~mc1 & vmaskw(g * 4 + 1);
        U64 ns2 = ~mc2 & vmaskw(g * 4 + 2), ns3 = ~mc3 & vmaskw(g * 4 + 3);
        U64 k0 = 0, k1 = 0, k2 = 0, k3 = 0;
        while (ns0) {
            int i = (int)__builtin_ctzll(ns0);
            k0 |= 1ull << i;
            ns0 &= ~(rdlane64(c00, i) | (1ull << i));
            ns1 &= ~rdlane64(c10, i);
            ns2 &= ~rdlane64(c20, i);
            ns3 &= ~rdlane64(c30, i);
        }
        while (ns1) {
            int i = (int)__builtin_ctzll(ns1);
            k1 |= 1ull << i;
            ns1 &= ~(rdlane64(c11, i) | (1ull << i));
            ns2 &= ~rdlane64(c21, i);
            ns3 &= ~rdlane64(c31, i);
        }
        while (ns2) {
            int i = (int)__builtin_ctzll(ns2);
            k2 |= 1ull << i;
            ns2 &= ~(rdlane64(c22, i) | (1ull << i));
            ns3 &= ~rdlane64(c32, i);
        }
        while (ns3) {
            int i = (int)__builtin_ctzll(ns3);
            k3 |= 1ull << i;
            ns3 &= ~(rdlane64(c33, i) | (1ull << i));
        }
        unsigned p0 = (unsigned)__popcll(k0), p1 = (unsigned)__popcll(k1);
        unsigned p2 = (unsigned)__popcll(k2), p3 = (unsigned)__popcll(k3);
        U64 lmask = (1ull << lane) - 1ull;
        if ((k0 >> lane) & 1) {
            unsigned dst = base + (unsigned)__popcll(k0 & lmask);
            reinterpret_cast<float4*>(rois_out)[dst] = reinterpret_cast<const float4*>(sboxes)[gbase + lane];
            keep_out[dst] = 1.0f;
        }
        if ((k1 >> lane) & 1) {
            unsigned dst = base + p0 + (unsigned)__popcll(k1 & lmask);
            reinterpret_cast<float4*>(rois_out)[dst] = reinterpret_cast<const float4*>(sboxes)[gbase + 64 + lane];
            keep_out[dst] = 1.0f;
        }
        if ((k2 >> lane) & 1) {
            unsigned dst = base + p0 + p1 + (unsigned)__popcll(k2 & lmask);
            reinterpret_cast<float4*>(rois_out)[dst] = reinterpret_cast<const float4*>(sboxes)[gbase + 128 + lane];
            keep_out[dst] = 1.0f;
        }
        if ((k3 >> lane) & 1) {
            unsigned dst = base + p0 + p1 + p2 + (unsigned)__popcll(k3 & lmask);
            reinterpret_cast<float4*>(rois_out)[dst] = reinterpret_cast<const float4*>(sboxes)[gbase + 192 + lane];
            keep_out[dst] = 1.0f;
        }
        base += p0 + p1 + p2 + p3;

        const int wmin = g * 4 + 4;
        const bool gw0 = (lane >= wmin);
        const bool gw1 = (64 + lane >= wmin);
        const bool gw2 = (128 + lane >= wmin);
        const bool gw3 = (192 + lane >= wmin);
        const bool gw4 = (256 + lane >= wmin) && (256 + lane < NW);
        U64 kk0 = k0, kk1 = k1, kk2 = k2, kk3 = k3;
        bool any = (kk0 | kk1 | kk2 | kk3) != 0;
        while (kk0 | kk1 | kk2 | kk3) {
            POPR(ra); POPR(rb); POPR(rc); POPR(rd);
            if (rb < 0) rb = ra;
            if (rc < 0) rc = ra;
            if (rd < 0) rd = ra;
            const U64* qa = mask + (size_t)(gbase + ra) * MSTRIDE + lane;
            const U64* qb = mask + (size_t)(gbase + rb) * MSTRIDE + lane;
            const U64* qc = mask + (size_t)(gbase + rc) * MSTRIDE + lane;
            const U64* qd = mask + (size_t)(gbase + rd) * MSTRIDE + lane;
            U64 va0, va1, va2, va3, va4, vb0, vb1, vb2, vb3, vb4;
            U64 vc0, vc1, vc2, vc3, vc4, vd0, vd1, vd2, vd3, vd4;
            GLOAD64(va0, qa);       GLOAD64(va1, qa + 64);  GLOAD64(va2, qa + 128);
            GLOAD64(va3, qa + 192); GLOAD64(va4, qa + 256);
            GLOAD64(vb0, qb);       GLOAD64(vb1, qb + 64);  GLOAD64(vb2, qb + 128);
            GLOAD64(vb3, qb + 192); GLOAD64(vb4, qb + 256);
            GLOAD64(vc0, qc);       GLOAD64(vc1, qc + 64);  GLOAD64(vc2, qc + 128);
            GLOAD64(vc3, qc + 192); GLOAD64(vc4, qc + 256);
            GLOAD64(vd0, qd);       GLOAD64(vd1, qd + 64);  GLOAD64(vd2, qd + 128);
            GLOAD64(vd3, qd + 192); GLOAD64(vd4, qd + 256);
            VWAIT0();
            if (gw0) m0 |= va0 | vb0 | vc0 | vd0;
            if (gw1) m1 |= va1 | vb1 | vc1 | vd1;
            if (gw2) m2 |= va2 | vb2 | vc2 | vd2;
            if (gw3) m3 |= va3 | vb3 | vc3 | vd3;
            if (gw4) m4 |= va4 | vb4 | vc4 | vd4;
        }
        if (!any) VWAIT0();

        c00 = n00; c01 = n01; c02 = n02; c03 = n03;
        c10 = n10; c11 = n11; c12 = n12; c13 = n13;
        c20 = n20; c21 = n21; c22 = n22; c23 = n23;
        c30 = n30; c31 = n31; c32 = n32; c33 = n33;
    }
}

// ---------------- launch ----------------
extern "C" void kernel_launch(void* const* d_in, const int* in_sizes, int n_in,
                              void* d_out, int out_size, void* d_ws, size_t ws_size,
                              hipStream_t stream) {
    const float* fm      = (const float*)d_in[0];
    const float* conv_w  = (const float*)d_in[2];
    const float* conv_b  = (const float*)d_in[3];
    const float* score_w = (const float*)d_in[4];
    const float* score_b = (const float*)d_in[5];
    const float* loc_w   = (const float*)d_in[6];
    const float* loc_b   = (const float*)d_in[7];

    float* out = (float*)d_out;
    float* rois_out  = out;
    float* keep_out  = out + NBOX * 4;
    float* anch_out  = out + NBOX * 5;
    float* loc_out   = out + NBOX * 9;
    float* score_out = out + NBOX * 13;

    if (ws_size < WS_NEED) {
        k_sentinel<<<(out_size + 255) / 256, 256, 0, stream>>>(out, out_size);
        return;
    }

    char* ws = (char*)d_ws;
    float* in_tT   = (float*)(ws + OFF_INT);
    float* w2      = (float*)(ws + OFF_WT);
    float* partial = (float*)(ws + OFF_PART);
    U64*   mask    = (U64*)(ws + OFF_MASK);
    U64*   diagX   = (U64*)(ws + OFF_DIAG);
    float* mid     = (float*)(ws + OFF_MID);   // aliases partial slice 0
    float* fg      = (float*)(ws + OFF_FG);
    float* boxes   = (float*)(ws + OFF_BOX);
    float* sboxes  = (float*)(ws + OFF_SBOX);
    float* sarea   = (float*)(ws + OFF_SAREA);
    int*   cntb    = (int*)(ws + OFF_CNT);

    hipMemsetAsync(in_tT, 0, SZ_INT, stream);
    k_in_t<<<(CIN * H * W + 255) / 256, 256, 0, stream>>>(fm, in_tT);
    k_w_t<<<(CMID * CIN * 9 + 255) / 256, 256, 0, stream>>>(conv_w, w2);
    k_conv<<<1024, 256, 0, stream>>>(in_tT, w2, partial);
    k_reduce<<<P, 256, 0, stream>>>(partial, conv_b, mid);
    k_heads<<<(P + 15) / 16, 256, 0, stream>>>(mid, score_w, score_b, loc_w, loc_b,
                                               score_out, loc_out, anch_out, fg, boxes);
    hipMemsetAsync(cntb, 0, NBOX * 4, stream);
    k_rank_part<<<dim3((NBOX + 255) / 256, 8), 256, 0, stream>>>(fg, cntb);
    k_scatter<<<(NBOX + 255) / 256, 256, 0, stream>>>(cntb, boxes, sboxes, sarea);
    hipMemsetAsync(rois_out, 0, (size_t)NBOX * 5 * 4, stream);  // rois_out + keep
    hipMemsetAsync(diagX, 0, SZ_DIAG, stream);
    k_maskfill<<<dim3((NBOX + 255) / 256, NW), 256, 0, stream>>>(sboxes, sarea, mask, diagX);
    k_sweep<<<1, 64, 0, stream>>>(mask, diagX, sboxes, rois_out, keep_out);
}

// Round 22
// 725.867 us; speedup vs baseline: 1.1136x; 1.0029x over previous
//
#include <hip/hip_runtime.h>
#include <cstdint>

#define U64 unsigned long long

static constexpr int H = 38, W = 50, P = 1900;        // feature map
static constexpr int CIN = 2048, CMID = 256;
static constexpr int NA = 9, NBOX = 17100;            // 1900*9
static constexpr int HP = 40, WP = 52, QP = HP * WP;  // padded positions (2080)
static constexpr int TPITCH = 2084;                   // in_tT row pitch (floats), mult of 4
static constexpr int KS = 8;                          // split-K over cin (8 x 256)
static constexpr int NW = 268;                        // u64 words covering NBOX bits
static constexpr int MSTRIDE = 272;                   // mask row stride (words)
static constexpr int NG = 67;                         // 256-box groups
static constexpr float NMS_T = 0.5f;
static constexpr int QTILE = 128;                     // proven optimum (299/277/336 for 256/128/64)
static constexpr int SROW = 244;                      // s_in row stride (floats)

// ---------------- ws layout (bytes) ----------------
static constexpr size_t SZ_INT  = (size_t)CIN * TPITCH * 4;   // 17,072,128
static constexpr size_t SZ_WT   = (size_t)9 * CIN * CMID * 4; // 18,874,368
static constexpr size_t SZ_PART = (size_t)KS * P * CMID * 4;  // 15,564,800
static constexpr size_t OFF_INT  = 0;
static constexpr size_t OFF_WT   = OFF_INT + SZ_INT;
static constexpr size_t OFF_PART = OFF_WT + SZ_WT;            // 35,946,496
static constexpr size_t REGA     = OFF_PART + SZ_PART;        // 51,511,296
// region A overlay (dead after k_reduce): mask + diag 256-blocks
static constexpr size_t OFF_MASK = 0;                          // mask [NBOX][MSTRIDE] (37.2 MB)
static constexpr size_t SZ_MASK  = (size_t)NBOX * MSTRIDE * 8; // 37,209,600
static constexpr size_t OFF_DIAG = SZ_MASK;                    // diagX [67][4][4][64] u64 (549 KB)
static constexpr size_t SZ_DIAG  = (size_t)NG * 1024 * 8;      // 548,864
static constexpr size_t OFF_MID  = OFF_PART;                   // mid ALIASES partial slice 0
                                                               // (k_reduce reads-then-writes per elem;
                                                               //  mid dead before maskfill overlay)
static constexpr size_t OFF_FG   = REGA;                       // 51,511,296
static constexpr size_t OFF_BOX  = OFF_FG + 68608;
static constexpr size_t OFF_SBOX = OFF_BOX + 273664;
static constexpr size_t OFF_SAREA= OFF_SBOX + 273664;
static constexpr size_t OFF_CNT  = OFF_SAREA + 68608;
static constexpr size_t WS_NEED  = OFF_CNT + 68608;            // 52,264,448 (unchanged)

__device__ __forceinline__ U64 rdlane64(U64 v, int l) {
    unsigned lo = (unsigned)__builtin_amdgcn_readlane((int)(unsigned)(v & 0xffffffffull), l);
    unsigned hi = (unsigned)__builtin_amdgcn_readlane((int)(unsigned)(v >> 32), l);
    return ((U64)hi << 32) | (U64)lo;
}

__device__ __forceinline__ U64 vmaskw(int wg) {
    int rem = NBOX - wg * 64;
    if (rem >= 64) return ~0ull;
    if (rem <= 0) return 0ull;
    return (1ull << rem) - 1ull;
}

// ---------------- kernels ----------------

__global__ __launch_bounds__(256) void k_sentinel(float* out, int n) {
    int i = blockIdx.x * 256 + threadIdx.x;
    if (i < n) out[i] = 1.2345678e8f;
}

// feature_map [CIN][H][W] -> in_tT [CIN][TPITCH] (padded image rows; memset first)
__global__ __launch_bounds__(256) void k_in_t(const float* __restrict__ fm, float* __restrict__ in_tT) {
    int idx = blockIdx.x * 256 + threadIdx.x;
    if (idx >= CIN * (H * W)) return;
    int ci = idx / (H * W), hw = idx - ci * (H * W);
    int h = hw / W, w = hw - h * W;
    in_tT[(size_t)ci * TPITCH + (h + 1) * WP + 1 + w] = fm[idx];
}

// conv_w [CMID][CIN][3][3] -> w2 [y(8)][sub(4)][ci(2048)][k(9)][c(8)]
__global__ __launch_bounds__(256) void k_w_t(const float* __restrict__ cw, float* __restrict__ w2) {
    int idx = blockIdx.x * 256 + threadIdx.x;
    if (idx >= CMID * CIN * 9) return;
    int co = idx / (CIN * 9);
    int rem = idx - co * (CIN * 9);
    int ci = rem / 9, k = rem - ci * 9;
    w2[((size_t)(co >> 3) * CIN + ci) * 72 + k * 8 + (co & 7)] = cw[idx];
}

// 3x3 conv, split-K. grid 1024 = 16 qtiles of 128 x 8 cout-groups x 8 z
// (XCD-swizzled, z-major; exactly 4 blocks/CU). Lane L owns q in {q0+L, q0+64+L};
// scalar stride-1 LDS reads (proven conflict-free, 0 conflicts round 16/19/20).
__global__ __launch_bounds__(256, 2) void k_conv(const float* __restrict__ in_tT,
                                                 const float* __restrict__ w2,
                                                 float* __restrict__ partial) {
    __shared__ float s_in[16 * SROW];    // 16 ci x 244 floats (15.6 KB)
    int t = threadIdx.x;
    int lane = t & 63;
    int sub = __builtin_amdgcn_readfirstlane(t >> 6);   // wave-uniform SGPR

    int raw = blockIdx.x;
    int xcd = raw & 7, i0 = raw >> 3;
    int L = xcd * 128 + i0;          // 1024 = 8*128, bijective
    int z = L >> 7;                  // 8 z-slices (128 blocks each)
    int r0 = L & 127;
    int by = r0 >> 4, bx = r0 & 15;
    int q0 = bx * QTILE;
    int cout0 = by * 32;
    int cin0 = z * 256;
    int cin1 = cin0 + 256;

    float acc[2][8];
#pragma unroll
    for (int j = 0; j < 2; ++j)
#pragma unroll
        for (int c = 0; c < 8; ++c) acc[j][c] = 0.f;

    const float* wbase = w2 + (size_t)(by * 4 + sub) * CIN * 72;

    for (int c0 = cin0; c0 < cin1; c0 += 16) {
        // stage 16 ci rows: 61 quads each covering q in [q0-56, q0+187]
        for (int idx = t; idx < 16 * 61; idx += 256) {
            int r = idx / 61, j = idx - r * 61;
            int qf = q0 - 56 + 4 * j;
            float4 v = make_float4(0.f, 0.f, 0.f, 0.f);
            if (qf >= 0 && qf <= 2080)
                v = *reinterpret_cast<const float4*>(in_tT + (size_t)(c0 + r) * TPITCH + qf);
            *reinterpret_cast<float4*>(s_in + r * SROW + 4 * j) = v;
        }
        __syncthreads();
#pragma unroll 1
        for (int r = 0; r < 16; ++r) {
            const float* si = s_in + r * SROW + lane + 56;
            const float4* w4 = reinterpret_cast<const float4*>(wbase + (size_t)(c0 + r) * 72);
#pragma unroll
            for (int k = 0; k < 9; ++k) {
                const int DQ[9] = {-53, -52, -51, -1, 0, 1, 51, 52, 53};
                float iv0 = si[DQ[k]];
                float iv1 = si[DQ[k] + 64];
                float4 wa = w4[k * 2], wb = w4[k * 2 + 1];
                acc[0][0] += iv0 * wa.x; acc[0][1] += iv0 * wa.y;
                acc[0][2] += iv0 * wa.z; acc[0][3] += iv0 * wa.w;
                acc[0][4] += iv0 * wb.x; acc[0][5] += iv0 * wb.y;
                acc[0][6] += iv0 * wb.z; acc[0][7] += iv0 * wb.w;
                acc[1][0] += iv1 * wa.x; acc[1][1] += iv1 * wa.y;
                acc[1][2] += iv1 * wa.z; acc[1][3] += iv1 * wa.w;
                acc[1][4] += iv1 * wb.x; acc[1][5] += iv1 * wb.y;
                acc[1][6] += iv1 * wb.z; acc[1][7] += iv1 * wb.w;
            }
        }
        __syncthreads();
    }
    float* part = partial + (size_t)z * P * CMID;
#pragma unroll
    for (int jj = 0; jj < 2; ++jj) {
        int q = q0 + lane + 64 * jj;
        if (q < QP) {
            int hp = q / WP, wp_ = q - hp * WP;
            if (hp >= 1 && hp <= H && wp_ >= 1 && wp_ <= W) {
                int p = (hp - 1) * W + (wp_ - 1);
                float* dst = part + (size_t)p * CMID + cout0 + sub * 8;
                float4* d4 = reinterpret_cast<float4*>(dst);
                d4[0] = make_float4(acc[jj][0], acc[jj][1], acc[jj][2], acc[jj][3]);
                d4[1] = make_float4(acc[jj][4], acc[jj][5], acc[jj][6], acc[jj][7]);
            }
        }
    }
}

// sum partials + bias + relu -> mid [P][CMID]  (mid aliases partial slice 0;
// each thread reads all its slices before writing its own element)
__global__ __launch_bounds__(256) void k_reduce(const float* __restrict__ partial,
                                                const float* __restrict__ bias,
                                                float* __restrict__ mid) {
    int p = blockIdx.x, c = threadIdx.x;
    float s = bias[c];
    for (int ks = 0; ks < KS; ++ks) s += partial[(size_t)ks * P * CMID + (size_t)p * CMID + c];
    mid[(size_t)p * CMID + c] = fmaxf(s, 0.f);
}

// 1x1 heads + softmax + anchors + loc2bbox + clip. 16 positions per block (4 reps).
__global__ __launch_bounds__(256) void k_heads(const float* __restrict__ mid,
                                               const float* __restrict__ score_w,
                                               const float* __restrict__ score_b,
                                               const float* __restrict__ loc_w,
                                               const float* __restrict__ loc_b,
                                               float* __restrict__ score_out,
                                               float* __restrict__ loc_out,
                                               float* __restrict__ anch_out,
                                               float* __restrict__ fg,
                                               float* __restrict__ boxes) {
    __shared__ float wl[256][56];
    __shared__ float bias[56];
    __shared__ float dots[4][64];
    int t = threadIdx.x;
    for (int idx = t; idx < 18 * 256; idx += 256) {
        int c = idx >> 8, i = idx & 255;
        wl[i][c] = score_w[idx];
    }
    for (int idx = t; idx < 36 * 256; idx += 256) {
        int c = idx >> 8, i = idx & 255;
        wl[i][18 + c] = loc_w[idx];
    }
    if (t < 18) bias[t] = score_b[t];
    else if (t < 54) bias[t] = loc_b[t - 18];
    __syncthreads();

    int pl = t >> 6, c = t & 63;
    for (int rep = 0; rep < 4; ++rep) {
        int p = blockIdx.x * 16 + rep * 4 + pl;
        if (c < 54 && p < P) {
            float d = bias[c];
            const float4* mp = reinterpret_cast<const float4*>(mid + (size_t)p * CMID);
            for (int i4 = 0; i4 < 64; ++i4) {
                float4 m4 = mp[i4];
                int i = i4 * 4;
                d += m4.x * wl[i][c] + m4.y * wl[i + 1][c] + m4.z * wl[i + 2][c] + m4.w * wl[i + 3][c];
            }
            dots[pl][c] = d;
        }
        __syncthreads();
        if (c < NA && p < P) {
            int a = c;
            int idx = p * NA + a;
            float l0 = dots[pl][2 * a], l1 = dots[pl][2 * a + 1];
            float mx = fmaxf(l0, l1);
            float e0 = expf(l0 - mx), e1 = expf(l1 - mx);
            float den = e0 + e1;
            float s0 = e0 / den, s1 = e1 / den;
            score_out[(size_t)idx * 2 + 0] = s0;
            score_out[(size_t)idx * 2 + 1] = s1;
            fg[idx] = s1;
            float dx = dots[pl][18 + 4 * a + 0];
            float dy = dots[pl][18 + 4 * a + 1];
            float dw = dots[pl][18 + 4 * a + 2];
            float dh = dots[pl][18 + 4 * a + 3];
            loc_out[(size_t)idx * 4 + 0] = dx;
            loc_out[(size_t)idx * 4 + 1] = dy;
            loc_out[(size_t)idx * 4 + 2] = dw;
            loc_out[(size_t)idx * 4 + 3] = dh;
            int hh = p / W, ww = p % W;
            const double scales[3] = {8.0, 16.0, 32.0};
            const double ratios[3] = {0.5, 1.0, 2.0};
            double s = scales[a / 3], r = ratios[a % 3];
            double wb2 = 16.0 * s * sqrt(r);
            double hb = wb2 / r;
            double xmin = 8.0 - wb2 / 2.0, ymin = 8.0 - hb / 2.0;
            float b0 = (float)xmin, b1 = (float)ymin;
            float b2 = (float)(xmin + wb2), b3 = (float)(ymin + hb);
            float gx = (float)(ww * 16), gy = (float)(hh * 16);
            float a0 = gx + b0, a1 = gy + b1, a2 = gx + b2, a3 = gy + b3;
            anch_out[(size_t)idx * 4 + 0] = a0;
            anch_out[(size_t)idx * 4 + 1] = a1;
            anch_out[(size_t)idx * 4 + 2] = a2;
            anch_out[(size_t)idx * 4 + 3] = a3;
            float aw = a2 - a0, ah = a3 - a1;
            float cx = a0 + 0.5f * aw, cy = a1 + 0.5f * ah;
            float ncx = dx * aw + cx, ncy = dy * ah + cy;
            float nw = expf(dw) * aw, nh = expf(dh) * ah;
            float x1 = ncx - 0.5f * nw, y1 = ncy - 0.5f * nh;
            float x2 = ncx + 0.5f * nw, y2 = ncy + 0.5f * nh;
            x1 = fminf(fmaxf(x1, 0.f), (float)(W * 16));
            x2 = fminf(fmaxf(x2, 0.f), (float)(W * 16));
            y1 = fminf(fmaxf(y1, 0.f), (float)(H * 16));
            y2 = fminf(fmaxf(y2, 0.f), (float)(H * 16));
            float4* bp = reinterpret_cast<float4*>(boxes);
            bp[idx] = make_float4(x1, y1, x2, y2);
        }
        __syncthreads();
    }
}

// partial stable-descending rank counts over a j-slice. grid (67, 8)
static constexpr int JSL = 2144;  // slice size (mult of 4)
__global__ __launch_bounds__(256) void k_rank_part(const float* __restrict__ fg,
                                                   int* __restrict__ cntb) {
    __shared__ float4 tile[256];
    int t = threadIdx.x;
    int i = blockIdx.x * 256 + t;
    int j0 = blockIdx.y * JSL;
    int j1 = min(NBOX, j0 + JSL);
    float my = (i < NBOX) ? fg[i] : 0.f;
    int cnt = 0;
    for (int base = j0; base < j1; base += 1024) {
        int j = base + t * 4;
        float4 v = make_float4(-3.4e38f, -3.4e38f, -3.4e38f, -3.4e38f);
        if (j + 3 < j1) {
            v = *reinterpret_cast<const float4*>(fg + j);
        } else {
            if (j < j1) v.x = fg[j];
            if (j + 1 < j1) v.y = fg[j + 1];
            if (j + 2 < j1) v.z = fg[j + 2];
            if (j + 3 < j1) v.w = fg[j + 3];
        }
        __syncthreads();
        tile[t] = v;
        __syncthreads();
        if (i < NBOX) {
            for (int u = 0; u < 256; ++u) {
                float4 s = tile[u];
                int jb = base + u * 4;
                cnt += (s.x > my) || (s.x == my && jb < i);
                cnt += (s.y > my) || (s.y == my && jb + 1 < i);
                cnt += (s.z > my) || (s.z == my && jb + 2 < i);
                cnt += (s.w > my) || (s.w == my && jb + 3 < i);
            }
        }
    }
    if (i < NBOX && cnt) atomicAdd(&cntb[i], cnt);
}

// scatter boxes to sorted order using rank counts
__global__ __launch_bounds__(256) void k_scatter(const int* __restrict__ cntb,
                                                 const float* __restrict__ boxes,
                                                 float* __restrict__ sboxes,
                                                 float* __restrict__ sarea) {
    int i = blockIdx.x * 256 + threadIdx.x;
    if (i >= NBOX) return;
    int c = cntb[i];
    float4 b = reinterpret_cast<const float4*>(boxes)[i];
    reinterpret_cast<float4*>(sboxes)[c] = b;
    sarea[c] = (b.z - b.x) * (b.w - b.y);
}

// NMS pair bitmask, row-major + diag 256-block bands (diagX memset 0 first).
__global__ __launch_bounds__(256) void k_maskfill(const float* __restrict__ sboxes,
                                                  const float* __restrict__ sarea,
                                                  U64* __restrict__ mask,
                                                  U64* __restrict__ diagX) {
    int w = blockIdx.y;
    int i0 = blockIdx.x * 256;
    if (w < (i0 >> 6)) return;
    __shared__ float4 sb[64];
    __shared__ float sa[64];
    int t = threadIdx.x;
    if (t < 64) {
        int j = w * 64 + t;
        if (j < NBOX) {
            sb[t] = reinterpret_cast<const float4*>(sboxes)[j];
            sa[t] = sarea[j];
        } else {
            sb[t] = make_float4(0.f, 0.f, 0.f, 0.f);
            sa[t] = 0.f;
        }
    }
    __syncthreads();
    int i = i0 + t;
    if (i >= NBOX || w < (i >> 6)) return;
    float4 bi = reinterpret_cast<const float4*>(sboxes)[i];
    float ai = sarea[i];
    U64 word = 0;
#pragma unroll 4
    for (int jb = 0; jb < 64; ++jb) {
        int j = w * 64 + jb;
        float4 bj = sb[jb];
        float xx1 = fmaxf(bi.x, bj.x), yy1 = fmaxf(bi.y, bj.y);
        float xx2 = fminf(bi.z, bj.z), yy2 = fminf(bi.w, bj.w);
        float inter = fmaxf(xx2 - xx1, 0.f) * fmaxf(yy2 - yy1, 0.f);
        float iou = inter / (ai + sa[jb] - inter);
        word |= ((U64)((iou > NMS_T) && (j > i))) << jb;
    }
    mask[(size_t)i * MSTRIDE + w] = word;
    int gi = i >> 8;
    int wl = w - gi * 4;
    if (wl >= 0 && wl < 4)
        diagX[(size_t)gi * 1024 + wl * 256 + (i & 255)] = word;
}

// ---- sweep v9: single wave, asm-pinned pipeline (round-12, unchanged).
#define GLOAD64(dst, addr) \
    asm volatile("global_load_dwordx2 %0, %1, off" : "=v"(dst) : "v"(addr))

#define VWAIT0() do { asm volatile("s_waitcnt vmcnt(0)" ::: "memory"); \
                      __builtin_amdgcn_sched_barrier(0); } while (0)

#define DVARS(P) U64 P##00, P##01, P##02, P##03, P##10, P##11, P##12, P##13, \
                     P##20, P##21, P##22, P##23, P##30, P##31, P##32, P##33

#define DISSUE(P, G) do { \
    const U64* _dp = diagX + (size_t)(G) * 1024 + lane; \
    GLOAD64(P##00, _dp +   0); GLOAD64(P##01, _dp +  64); GLOAD64(P##02, _dp + 128); GLOAD64(P##03, _dp + 192); \
    GLOAD64(P##10, _dp + 256); GLOAD64(P##11, _dp + 320); GLOAD64(P##12, _dp + 384); GLOAD64(P##13, _dp + 448); \
    GLOAD64(P##20, _dp + 512); GLOAD64(P##21, _dp + 576); GLOAD64(P##22, _dp + 640); GLOAD64(P##23, _dp + 704); \
    GLOAD64(P##30, _dp + 768); GLOAD64(P##31, _dp + 832); GLOAD64(P##32, _dp + 896); GLOAD64(P##33, _dp + 960); \
} while (0)

#define ZEROD(P) do { \
    P##00 = P##01 = P##02 = P##03 = P##10 = P##11 = P##12 = P##13 = 0; \
    P##20 = P##21 = P##22 = P##23 = P##30 = P##31 = P##32 = P##33 = 0; \
} while (0)

#define POPR(R) \
    int R; \
    do { \
        if (kk0) { int _i = (int)__builtin_ctzll(kk0); kk0 &= kk0 - 1; R = _i; } \
        else if (kk1) { int _i = (int)__builtin_ctzll(kk1); kk1 &= kk1 - 1; R = 64 + _i; } \
        else if (kk2) { int _i = (int)__builtin_ctzll(kk2); kk2 &= kk2 - 1; R = 128 + _i; } \
        else if (kk3) { int _i = (int)__builtin_ctzll(kk3); kk3 &= kk3 - 1; R = 192 + _i; } \
        else R = -1; \
    } while (0)

__global__ __launch_bounds__(64, 1) void k_sweep(const U64* __restrict__ mask,
                                                 const U64* __restrict__ diagX,
                                                 const float* __restrict__ sboxes,
                                                 float* __restrict__ rois_out,
                                                 float* __restrict__ keep_out) {
    int lane = threadIdx.x;
    U64 m0 = 0, m1 = 0, m2 = 0, m3 = 0, m4 = 0;
    unsigned base = 0;
    DVARS(c);
    DVARS(n);
    DISSUE(c, 0);
    VWAIT0();

    for (int g = 0; g < NG; ++g) {
        if (g + 1 < NG) { DISSUE(n, g + 1); } else { ZEROD(n); }

        const int gbase = g * 256;
        int rsel = g >> 4;
        U64 msel = (rsel == 0) ? m0 : (rsel == 1) ? m1 : (rsel == 2) ? m2 : (rsel == 3) ? m3 : m4;
        int lb = (g * 4) & 63;
        U64 mc0 = rdlane64(msel, lb), mc1 = rdlane64(msel, lb + 1);
        U64 mc2 = rdlane64(msel, lb + 2), mc3 = rdlane64(msel, lb + 3);
        U64 ns0 = ~mc0 & vmaskw(g * 4),     ns1 = ~mc1 & vmaskw(g * 4 + 1);
        U64 ns2 = ~mc2 & vmaskw(g * 4 + 2), ns3 = ~mc3 & vmaskw(g * 4 + 3);
        U64 k0 = 0, k1 = 0, k2 = 0, k3 = 0;
        while (ns0) {
            int i = (int)__builtin_ctzll(ns0);
            k0 |= 1ull << i;
            ns0 &= ~(rdlane64(c00, i) | (1ull << i));
            ns1 &= ~rdlane64(c10, i);
            ns2 &= ~rdlane64(c20, i);
            ns3 &= ~rdlane64(c30, i);
        }
        while (ns1) {
            int i = (int)__builtin_ctzll(ns1);
            k1 |= 1ull << i;
            ns1 &= ~(rdlane64(c11, i) | (1ull << i));
            ns2 &= ~rdlane64(c21, i);
            ns3 &= ~rdlane64(c31, i);
        }
        while (ns2) {
            int i = (int)__builtin_ctzll(ns2);
            k2 |= 1ull << i;
            ns2 &= ~(rdlane64(c22, i) | (1ull << i));
            ns3 &= ~rdlane64(c32, i);
        }
        while (ns3) {
            int i = (int)__builtin_ctzll(ns3);
            k3 |= 1ull << i;
            ns3 &= ~(rdlane64(c33, i) | (1ull << i));
        }
        unsigned p0 = (unsigned)__popcll(k0), p1 = (unsigned)__popcll(k1);
        unsigned p2 = (unsigned)__popcll(k2), p3 = (unsigned)__popcll(k3);
        U64 lmask = (1ull << lane) - 1ull;
        if ((k0 >> lane) & 1) {
            unsigned dst = base + (unsigned)__popcll(k0 & lmask);
            reinterpret_cast<float4*>(rois_out)[dst] = reinterpret_cast<const float4*>(sboxes)[gbase + lane];
            keep_out[dst] = 1.0f;
        }
        if ((k1 >> lane) & 1) {
            unsigned dst = base + p0 + (unsigned)__popcll(k1 & lmask);
            reinterpret_cast<float4*>(rois_out)[dst] = reinterpret_cast<const float4*>(sboxes)[gbase + 64 + lane];
            keep_out[dst] = 1.0f;
        }
        if ((k2 >> lane) & 1) {
            unsigned dst = base + p0 + p1 + (unsigned)__popcll(k2 & lmask);
            reinterpret_cast<float4*>(rois_out)[dst] = reinterpret_cast<const float4*>(sboxes)[gbase + 128 + lane];
            keep_out[dst] = 1.0f;
        }
        if ((k3 >> lane) & 1) {
            unsigned dst = base + p0 + p1 + p2 + (unsigned)__popcll(k3 & lmask);
            reinterpret_cast<float4*>(rois_out)[dst] = reinterpret_cast<const float4*>(sboxes)[gbase + 192 + lane];
            keep_out[dst] = 1.0f;
        }
        base += p0 + p1 + p2 + p3;

        const int wmin = g * 4 + 4;
        const bool gw0 = (lane >= wmin);
        const bool gw1 = (64 + lane >= wmin);
        const bool gw2 = (128 + lane >= wmin);
        const bool gw3 = (192 + lane >= wmin);
        const bool gw4 = (256 + lane >= wmin) && (256 + lane < NW);
        U64 kk0 = k0, kk1 = k1, kk2 = k2, kk3 = k3;
        bool any = (kk0 | kk1 | kk2 | kk3) != 0;
        while (kk0 | kk1 | kk2 | kk3) {
            POPR(ra); POPR(rb); POPR(rc); POPR(rd);
            if (rb < 0) rb = ra;
            if (rc < 0) rc = ra;
            if (rd < 0) rd = ra;
            const U64* qa = mask + (size_t)(gbase + ra) * MSTRIDE + lane;
            const U64* qb = mask + (size_t)(gbase + rb) * MSTRIDE + lane;
            const U64* qc = mask + (size_t)(gbase + rc) * MSTRIDE + lane;
            const U64* qd = mask + (size_t)(gbase + rd) * MSTRIDE + lane;
            U64 va0, va1, va2, va3, va4, vb0, vb1, vb2, vb3, vb4;
            U64 vc0, vc1, vc2, vc3, vc4, vd0, vd1, vd2, vd3, vd4;
            GLOAD64(va0, qa);       GLOAD64(va1, qa + 64);  GLOAD64(va2, qa + 128);
            GLOAD64(va3, qa + 192); GLOAD64(va4, qa + 256);
            GLOAD64(vb0, qb);       GLOAD64(vb1, qb + 64);  GLOAD64(vb2, qb + 128);
            GLOAD64(vb3, qb + 192); GLOAD64(vb4, qb + 256);
            GLOAD64(vc0, qc);       GLOAD64(vc1, qc + 64);  GLOAD64(vc2, qc + 128);
            GLOAD64(vc3, qc + 192); GLOAD64(vc4, qc + 256);
            GLOAD64(vd0, qd);       GLOAD64(vd1, qd + 64);  GLOAD64(vd2, qd + 128);
            GLOAD64(vd3, qd + 192); GLOAD64(vd4, qd + 256);
            VWAIT0();
            if (gw0) m0 |= va0 | vb0 | vc0 | vd0;
            if (gw1) m1 |= va1 | vb1 | vc1 | vd1;
            if (gw2) m2 |= va2 | vb2 | vc2 | vd2;
            if (gw3) m3 |= va3 | vb3 | vc3 | vd3;
            if (gw4) m4 |= va4 | vb4 | vc4 | vd4;
        }
        if (!any) VWAIT0();

        c00 = n00; c01 = n01; c02 = n02; c03 = n03;
        c10 = n10; c11 = n11; c12 = n12; c13 = n13;
        c20 = n20; c21 = n21; c22 = n22; c23 = n23;
        c30 = n30; c31 = n31; c32 = n32; c33 = n33;
    }
}

// ---------------- launch ----------------
extern "C" void kernel_launch(void* const* d_in, const int* in_sizes, int n_in,
                              void* d_out, int out_size, void* d_ws, size_t ws_size,
                              hipStream_t stream) {
    const float* fm      = (const float*)d_in[0];
    const float* conv_w  = (const float*)d_in[2];
    const float* conv_b  = (const float*)d_in[3];
    const float* score_w = (const float*)d_in[4];
    const float* score_b = (const float*)d_in[5];
    const float* loc_w   = (const float*)d_in[6];
    const float* loc_b   = (const float*)d_in[7];

    float* out = (float*)d_out;
    float* rois_out  = out;
    float* keep_out  = out + NBOX * 4;
    float* anch_out  = out + NBOX * 5;
    float* loc_out   = out + NBOX * 9;
    float* score_out = out + NBOX * 13;

    if (ws_size < WS_NEED) {
        k_sentinel<<<(out_size + 255) / 256, 256, 0, stream>>>(out, out_size);
        return;
    }

    char* ws = (char*)d_ws;
    float* in_tT   = (float*)(ws + OFF_INT);
    float* w2      = (float*)(ws + OFF_WT);
    float* partial = (float*)(ws + OFF_PART);
    U64*   mask    = (U64*)(ws + OFF_MASK);
    U64*   diagX   = (U64*)(ws + OFF_DIAG);
    float* mid     = (float*)(ws + OFF_MID);   // aliases partial slice 0
    float* fg      = (float*)(ws + OFF_FG);
    float* boxes   = (float*)(ws + OFF_BOX);
    float* sboxes  = (float*)(ws + OFF_SBOX);
    float* sarea   = (float*)(ws + OFF_SAREA);
    int*   cntb    = (int*)(ws + OFF_CNT);

    hipMemsetAsync(in_tT, 0, SZ_INT, stream);
    k_in_t<<<(CIN * H * W + 255) / 256, 256, 0, stream>>>(fm, in_tT);
    k_w_t<<<(CMID * CIN * 9 + 255) / 256, 256, 0, stream>>>(conv_w, w2);
    k_conv<<<1024, 256, 0, stream>>>(in_tT, w2, partial);
    k_reduce<<<P, 256, 0, stream>>>(partial, conv_b, mid);
    k_heads<<<(P + 15) / 16, 256, 0, stream>>>(mid, score_w, score_b, loc_w, loc_b,
                                               score_out, loc_out, anch_out, fg, boxes);
    hipMemsetAsync(cntb, 0, NBOX * 4, stream);
    k_rank_part<<<dim3((NBOX + 255) / 256, 8), 256, 0, stream>>>(fg, cntb);
    k_scatter<<<(NBOX + 255) / 256, 256, 0, stream>>>(cntb, boxes, sboxes, sarea);
    hipMemsetAsync(rois_out, 0, (size_t)NBOX * 5 * 4, stream);  // rois_out + keep
    hipMemsetAsync(diagX, 0, SZ_DIAG, stream);
    k_maskfill<<<dim3((NBOX + 255) / 256, NW), 256, 0, stream>>>(sboxes, sarea, mask, diagX);
    k_sweep<<<1, 64, 0, stream>>>(mask, diagX, sboxes, rois_out, keep_out);
}